// Round 1
// baseline (577.290 us; speedup 1.0000x reference)
//
#include <hip/hip_runtime.h>

// Problem constants (B=8,S=24,N=4096,K=9,C1=32,C2=16)
#define NB 8
#define NS 24
#define NN 4096
#define NK 9
#define NC1 32
#define NC2 16
#define BS_ (NB*NS)          // 192
#define BN_COUNT 32768.0f    // B*N elements per (s,o) for batchnorm

// ---------------------------------------------------------------------------
// Kernel 0: build gather tables.
//  G2T[m][r] (m<288, r<128): rem=r*288+m; k=rem>>12; n=rem&4095; = neigh[n*9+k]
//  G3T[m][r] (m<144, r<256): rem=r*144+m; same decomposition
//  W2T[m][o] (m<288, o<16):  = W2[o*288+m]   (for uniform 16B scalar loads)
// ---------------------------------------------------------------------------
__global__ void k_tables(const int* __restrict__ neigh,
                         int* __restrict__ G2T, int* __restrict__ G3T,
                         const float* __restrict__ W2, float* __restrict__ W2T) {
    int j = blockIdx.x * 256 + threadIdx.x;          // grid = 306*256 = 78336 exactly
    if (j < 36864) {                                 // G2T
        int m = j >> 7, r = j & 127;
        int rem = r * 288 + m;
        int k = rem >> 12, n = rem & 4095;
        G2T[j] = neigh[n * 9 + k];
    } else if (j < 73728) {                          // G3T
        int jj = j - 36864;
        int m = jj >> 8, r = jj & 255;
        int rem = r * 144 + m;
        int k = rem >> 12, n = rem & 4095;
        G3T[jj] = neigh[n * 9 + k];
    } else {                                         // W2T
        int jj = j - 73728;                          // jj < 4608
        int m = jj >> 4, o = jj & 15;
        W2T[jj] = W2[o * 288 + m];
    }
}

// ---------------------------------------------------------------------------
// Kernel 1: layer 1.  h[bs][c][n] = relu(b1[c] + sum_m W1[c,m]*F[n*9+m])
// where F is the (k,n)-transposed input slice. WG handles 512 points; the
// 4608 needed floats are a contiguous idx-range -> staged in LDS.
// ---------------------------------------------------------------------------
__global__ __launch_bounds__(256) void k_layer1(const float* __restrict__ input,
                                                const float* __restrict__ W1,
                                                const float* __restrict__ b1,
                                                float* __restrict__ h) {
    __shared__ float F[4608];
    int blk = blockIdx.x;                 // 1536 = 192 bs * 8 tiles
    int tile = blk & 7, bs = blk >> 3;
    const float* A = input + (size_t)bs * 36864;
    int I0 = tile * 4608;
    for (int j = threadIdx.x; j < 4608; j += 256) {
        int idx = I0 + j;
        int n = idx & 4095, k = idx >> 12;
        F[j] = A[n * 9 + k];
    }
    __syncthreads();
    float* hb = h + (size_t)bs * (NC1 * NN);
    for (int lp = threadIdx.x; lp < 512; lp += 256) {
        float v[9];
#pragma unroll
        for (int m = 0; m < 9; m++) v[m] = F[lp * 9 + m];
        int p = tile * 512 + lp;
#pragma unroll 4
        for (int c = 0; c < 32; c++) {
            float acc = b1[c];
#pragma unroll
            for (int m = 0; m < 9; m++) acc = fmaf(v[m], W1[c * 9 + m], acc);
            hb[c * NN + p] = fmaxf(acc, 0.f);
        }
    }
}

// ---------------------------------------------------------------------------
// Kernel 2: layer 2 + BN partial stats. WG per (bs, c): points p in
// [c*128,(c+1)*128) all read channel c of h -> stage 16KB slice in LDS.
// Thread t: r = t&127, K-half = t>>7, acc[16] over outputs.
// Weights via wave-uniform loads (scalar path), gathers via LDS.
// Deterministic per-WG stat partials (no atomics).
// ---------------------------------------------------------------------------
__global__ __launch_bounds__(256) void k_layer2(const float* __restrict__ h,
                                                const int* __restrict__ G2T,
                                                const float* __restrict__ W2T,
                                                const float* __restrict__ b2,
                                                float* __restrict__ y2,
                                                float* __restrict__ psum,
                                                float* __restrict__ psq) {
    __shared__ float hl[4096];
    __shared__ float red[128 * 16];
    __shared__ float wred[64];
    int blk = blockIdx.x;                 // 6144 = 192 bs * 32 c
    int c = blk & 31, bs = blk >> 5;
    const float* hb = h + ((size_t)bs * NC1 + c) * NN;
    for (int j = threadIdx.x; j < 4096; j += 256) hl[j] = hb[j];
    __syncthreads();

    int t = threadIdx.x;
    int r = t & 127, half = t >> 7;       // half is wave-uniform
    float acc[16];
#pragma unroll
    for (int o = 0; o < 16; o++) acc[o] = 0.f;

    const float4* W2T4 = (const float4*)W2T;
    int m0 = half * 144;
    for (int m = m0; m < m0 + 144; m++) {
        int g = G2T[m * 128 + r];         // coalesced, L2-hot table
        float val = hl[g];                // LDS gather
        float4 w0 = W2T4[(m << 2) + 0];   // wave-uniform -> s_load_dwordx4
        float4 w1 = W2T4[(m << 2) + 1];
        float4 w2 = W2T4[(m << 2) + 2];
        float4 w3 = W2T4[(m << 2) + 3];
        acc[0]  = fmaf(val, w0.x, acc[0]);  acc[1]  = fmaf(val, w0.y, acc[1]);
        acc[2]  = fmaf(val, w0.z, acc[2]);  acc[3]  = fmaf(val, w0.w, acc[3]);
        acc[4]  = fmaf(val, w1.x, acc[4]);  acc[5]  = fmaf(val, w1.y, acc[5]);
        acc[6]  = fmaf(val, w1.z, acc[6]);  acc[7]  = fmaf(val, w1.w, acc[7]);
        acc[8]  = fmaf(val, w2.x, acc[8]);  acc[9]  = fmaf(val, w2.y, acc[9]);
        acc[10] = fmaf(val, w2.z, acc[10]); acc[11] = fmaf(val, w2.w, acc[11]);
        acc[12] = fmaf(val, w3.x, acc[12]); acc[13] = fmaf(val, w3.y, acc[13]);
        acc[14] = fmaf(val, w3.z, acc[14]); acc[15] = fmaf(val, w3.w, acc[15]);
    }

    if (half == 1) {
#pragma unroll
        for (int o = 0; o < 16; o++) red[r * 16 + o] = acc[o];
    }
    __syncthreads();

    if (half == 0) {
        float s1[16], s2[16];
#pragma unroll
        for (int o = 0; o < 16; o++) {
            acc[o] += red[r * 16 + o];
            acc[o] += b2[o];
            s1[o] = acc[o];
            s2[o] = acc[o] * acc[o];
        }
        // y2[bs][o][n], n = c*128 + r  (coalesced per o)
        float* yb = y2 + (size_t)bs * NC2 * NN + (c * 128 + r);
#pragma unroll
        for (int o = 0; o < 16; o++) yb[o * NN] = acc[o];

        // wave reduction over 64 lanes (waves 0 and 1 hold half==0)
#pragma unroll
        for (int o = 0; o < 16; o++) {
            for (int off = 32; off; off >>= 1) {
                s1[o] += __shfl_down(s1[o], off);
                s2[o] += __shfl_down(s2[o], off);
            }
        }
        if ((t & 63) == 0) {
            int w = t >> 6;  // 0 or 1
#pragma unroll
            for (int o = 0; o < 16; o++) {
                wred[w * 16 + o]      = s1[o];
                wred[32 + w * 16 + o] = s2[o];
            }
        }
    }
    __syncthreads();
    if (t < 16) {
        float a = wred[t] + wred[16 + t];
        float b = wred[32 + t] + wred[48 + t];
        int srow = (bs % NS) * 16 + t;    // (s, o)
        int col  = (bs / NS) * 32 + c;    // (b, c)
        psum[srow * 256 + col] = a;
        psq [srow * 256 + col] = b;
    }
}

// ---------------------------------------------------------------------------
// Kernel 3: reduce BN partials -> scale/shift per (s,o). 384 WGs of 256.
// ---------------------------------------------------------------------------
__global__ __launch_bounds__(256) void k_bnstat(const float* __restrict__ psum,
                                                const float* __restrict__ psq,
                                                const float* __restrict__ gamma,
                                                const float* __restrict__ beta,
                                                float* __restrict__ scale,
                                                float* __restrict__ shift) {
    __shared__ float l1[4], l2[4];
    int row = blockIdx.x;
    int t = threadIdx.x;
    float s = psum[row * 256 + t], q = psq[row * 256 + t];
    for (int off = 32; off; off >>= 1) {
        s += __shfl_down(s, off);
        q += __shfl_down(q, off);
    }
    if ((t & 63) == 0) { l1[t >> 6] = s; l2[t >> 6] = q; }
    __syncthreads();
    if (t == 0) {
        s = l1[0] + l1[1] + l1[2] + l1[3];
        q = l2[0] + l2[1] + l2[2] + l2[3];
        float mean = s * (1.0f / BN_COUNT);
        float var  = q * (1.0f / BN_COUNT) - mean * mean;
        float inv  = rsqrtf(var + 1e-5f);
        int o = row & 15;
        float sc = gamma[o] * inv;
        scale[row] = sc;
        shift[row] = beta[o] - mean * sc;
    }
}

// ---------------------------------------------------------------------------
// Kernel 4: BN + relu + layer 3 + relu. WG per (bs, c2): stage normalized
// z-slice (16KB) in LDS, 144-tap gathered dot per point.
// ---------------------------------------------------------------------------
__global__ __launch_bounds__(256) void k_layer3(const float* __restrict__ y2,
                                                const int* __restrict__ G3T,
                                                const float* __restrict__ scale,
                                                const float* __restrict__ shift,
                                                const float* __restrict__ W3,
                                                const float* __restrict__ b3,
                                                float* __restrict__ out) {
    __shared__ float zl[4096];
    int blk = blockIdx.x;                 // 3072 = 192 bs * 16 c2
    int c2 = blk & 15, bs = blk >> 4;
    int s = bs % NS;
    float sc = scale[s * 16 + c2], sh = shift[s * 16 + c2];
    const float* yb = y2 + ((size_t)bs * NC2 + c2) * NN;
    for (int j = threadIdx.x; j < 4096; j += 256)
        zl[j] = fmaxf(fmaf(yb[j], sc, sh), 0.f);
    __syncthreads();
    int r = threadIdx.x;
    float acc = b3[0];
    for (int m = 0; m < 144; m++) {
        int g = G3T[m * 256 + r];         // coalesced
        acc = fmaf(zl[g], W3[m], acc);    // W3[m] wave-uniform -> scalar
    }
    out[(size_t)bs * NN + c2 * 256 + r] = fmaxf(acc, 0.f);
}

// ---------------------------------------------------------------------------
extern "C" void kernel_launch(void* const* d_in, const int* in_sizes, int n_in,
                              void* d_out, int out_size, void* d_ws, size_t ws_size,
                              hipStream_t stream) {
    const float* input = (const float*)d_in[0];
    const int*   neigh = (const int*)d_in[1];
    const float* W1    = (const float*)d_in[2];
    const float* b1    = (const float*)d_in[3];
    const float* W2    = (const float*)d_in[4];
    const float* b2    = (const float*)d_in[5];
    const float* gamma = (const float*)d_in[6];
    const float* beta  = (const float*)d_in[7];
    const float* W3    = (const float*)d_in[8];
    const float* b3    = (const float*)d_in[9];
    float* out = (float*)d_out;

    // Workspace layout (bytes), total ~152.1 MB
    char* ws = (char*)d_ws;
    int*   G2T   = (int*)  (ws);                      // 147456
    int*   G3T   = (int*)  (ws + 147456);             // 147456
    float* W2T   = (float*)(ws + 294912);             // 18432
    float* h     = (float*)(ws + 313344);             // 100663296
    float* y2    = (float*)(ws + 100976640);          // 50331648
    float* psum  = (float*)(ws + 151308288);          // 393216
    float* psq   = (float*)(ws + 151701504);          // 393216
    float* scale = (float*)(ws + 152094720);          // 1536
    float* shift = (float*)(ws + 152096256);          // 1536

    k_tables<<<306, 256, 0, stream>>>(neigh, G2T, G3T, W2, W2T);
    k_layer1<<<1536, 256, 0, stream>>>(input, W1, b1, h);
    k_layer2<<<6144, 256, 0, stream>>>(h, G2T, W2T, b2, y2, psum, psq);
    k_bnstat<<<384, 256, 0, stream>>>(psum, psq, gamma, beta, scale, shift);
    k_layer3<<<3072, 256, 0, stream>>>(y2, G3T, scale, shift, W3, b3, out);
}

// Round 2
// 266.752 us; speedup vs baseline: 2.1641x; 2.1641x over previous
//
#include <hip/hip_runtime.h>

// Problem constants (B=8,S=24,N=4096,K=9,C1=32,C2=16)
#define NB 8
#define NS 24
#define NN 4096
#define NK 9
#define NC1 32
#define NC2 16
#define BS_ (NB*NS)          // 192
#define BN_COUNT 32768.0f    // B*N elements per (s,o) for batchnorm

// ---------------------------------------------------------------------------
// Kernel 0: build gather tables.
//  G2T[m][r] (m<288, r<128): rem=r*288+m; k=rem>>12; n=rem&4095; = neigh[n*9+k]
//  G3T[m][r] (m<144, r<256): rem=r*144+m; same decomposition
//  W2T[m][o] (m<288, o<16):  = W2[o*288+m]   (for uniform 16B scalar loads)
// ---------------------------------------------------------------------------
__global__ void k_tables(const int* __restrict__ neigh,
                         int* __restrict__ G2T, int* __restrict__ G3T,
                         const float* __restrict__ W2, float* __restrict__ W2T) {
    int j = blockIdx.x * 256 + threadIdx.x;          // grid = 306*256 = 78336 exactly
    if (j < 36864) {                                 // G2T
        int m = j >> 7, r = j & 127;
        int rem = r * 288 + m;
        int k = rem >> 12, n = rem & 4095;
        G2T[j] = neigh[n * 9 + k];
    } else if (j < 73728) {                          // G3T
        int jj = j - 36864;
        int m = jj >> 8, r = jj & 255;
        int rem = r * 144 + m;
        int k = rem >> 12, n = rem & 4095;
        G3T[jj] = neigh[n * 9 + k];
    } else {                                         // W2T
        int jj = j - 73728;                          // jj < 4608
        int m = jj >> 4, o = jj & 15;
        W2T[jj] = W2[o * 288 + m];
    }
}

// ---------------------------------------------------------------------------
// Kernel 1: layer 1.  h[bs][c][n] = relu(b1[c] + sum_m W1[c,m]*F[n*9+m])
// ---------------------------------------------------------------------------
__global__ __launch_bounds__(256) void k_layer1(const float* __restrict__ input,
                                                const float* __restrict__ W1,
                                                const float* __restrict__ b1,
                                                float* __restrict__ h) {
    __shared__ float F[4608];
    int blk = blockIdx.x;                 // 1536 = 192 bs * 8 tiles
    int tile = blk & 7, bs = blk >> 3;
    const float* A = input + (size_t)bs * 36864;
    int I0 = tile * 4608;
    for (int j = threadIdx.x; j < 4608; j += 256) {
        int idx = I0 + j;
        int n = idx & 4095, k = idx >> 12;
        F[j] = A[n * 9 + k];
    }
    __syncthreads();
    float* hb = h + (size_t)bs * (NC1 * NN);
    for (int lp = threadIdx.x; lp < 512; lp += 256) {
        float v[9];
#pragma unroll
        for (int m = 0; m < 9; m++) v[m] = F[lp * 9 + m];
        int p = tile * 512 + lp;
#pragma unroll 4
        for (int c = 0; c < 32; c++) {
            float acc = b1[c];
#pragma unroll
            for (int m = 0; m < 9; m++) acc = fmaf(v[m], W1[c * 9 + m], acc);
            hb[c * NN + p] = fmaxf(acc, 0.f);
        }
    }
}

// ---------------------------------------------------------------------------
// Kernel 2: layer 2 + BN partial stats. WG per (bs, c). Weights are forced
// onto the SCALAR path via readfirstlane (half is wave-uniform by
// construction: waves 0,1 -> half=0, waves 2,3 -> half=1). Chunks of 8 give
// 8 outstanding VMEM index loads + 8 outstanding LDS gathers.
// ---------------------------------------------------------------------------
__global__ __launch_bounds__(256) void k_layer2(const float* __restrict__ h,
                                                const int* __restrict__ G2T,
                                                const float* __restrict__ W2T,
                                                const float* __restrict__ b2,
                                                float* __restrict__ y2,
                                                float* __restrict__ psum,
                                                float* __restrict__ psq) {
    __shared__ float hl[4096];
    __shared__ float red[128 * 16];
    __shared__ float wred[64];
    int blk = blockIdx.x;                 // 6144 = 192 bs * 32 c
    int c = blk & 31, bs = blk >> 5;
    const float* hb = h + ((size_t)bs * NC1 + c) * NN;
    for (int j = threadIdx.x; j < 4096; j += 256) hl[j] = hb[j];
    __syncthreads();

    int t = threadIdx.x;
    int r = t & 127, half = t >> 7;
    // half*144 is wave-uniform; readfirstlane makes the compiler SEE that,
    // so the weight loads below become s_load (K$) instead of per-lane VMEM.
    int m0 = __builtin_amdgcn_readfirstlane(half * 144);
    float acc[16];
#pragma unroll
    for (int o = 0; o < 16; o++) acc[o] = 0.f;

    const float4* W2T4 = (const float4*)W2T;
    const int* Gp = G2T + r;
    for (int mc = 0; mc < 144; mc += 8) {
        int gs[8];
        float vals[8];
#pragma unroll
        for (int j = 0; j < 8; j++) gs[j] = Gp[(m0 + mc + j) << 7];   // coalesced, L2-hot
#pragma unroll
        for (int j = 0; j < 8; j++) vals[j] = hl[gs[j]];              // LDS gather
#pragma unroll
        for (int j = 0; j < 8; j++) {
            const float4* wp = W2T4 + ((m0 + mc + j) << 2);           // scalar loads
            float4 w0 = wp[0], w1 = wp[1], w2 = wp[2], w3 = wp[3];
            float v = vals[j];
            acc[0]  = fmaf(v, w0.x, acc[0]);  acc[1]  = fmaf(v, w0.y, acc[1]);
            acc[2]  = fmaf(v, w0.z, acc[2]);  acc[3]  = fmaf(v, w0.w, acc[3]);
            acc[4]  = fmaf(v, w1.x, acc[4]);  acc[5]  = fmaf(v, w1.y, acc[5]);
            acc[6]  = fmaf(v, w1.z, acc[6]);  acc[7]  = fmaf(v, w1.w, acc[7]);
            acc[8]  = fmaf(v, w2.x, acc[8]);  acc[9]  = fmaf(v, w2.y, acc[9]);
            acc[10] = fmaf(v, w2.z, acc[10]); acc[11] = fmaf(v, w2.w, acc[11]);
            acc[12] = fmaf(v, w3.x, acc[12]); acc[13] = fmaf(v, w3.y, acc[13]);
            acc[14] = fmaf(v, w3.z, acc[14]); acc[15] = fmaf(v, w3.w, acc[15]);
        }
    }

    if (half == 1) {
#pragma unroll
        for (int o = 0; o < 16; o++) red[r * 16 + o] = acc[o];
    }
    __syncthreads();

    if (half == 0) {
        float s1[16], s2[16];
#pragma unroll
        for (int o = 0; o < 16; o++) {
            acc[o] += red[r * 16 + o];
            acc[o] += b2[o];
            s1[o] = acc[o];
            s2[o] = acc[o] * acc[o];
        }
        // y2[bs][o][n], n = c*128 + r  (coalesced per o)
        float* yb = y2 + (size_t)bs * NC2 * NN + (c * 128 + r);
#pragma unroll
        for (int o = 0; o < 16; o++) yb[o * NN] = acc[o];

        // wave reduction over 64 lanes (waves 0 and 1 hold half==0)
#pragma unroll
        for (int o = 0; o < 16; o++) {
            for (int off = 32; off; off >>= 1) {
                s1[o] += __shfl_down(s1[o], off);
                s2[o] += __shfl_down(s2[o], off);
            }
        }
        if ((t & 63) == 0) {
            int w = t >> 6;  // 0 or 1
#pragma unroll
            for (int o = 0; o < 16; o++) {
                wred[w * 16 + o]      = s1[o];
                wred[32 + w * 16 + o] = s2[o];
            }
        }
    }
    __syncthreads();
    if (t < 16) {
        float a = wred[t] + wred[16 + t];
        float b = wred[32 + t] + wred[48 + t];
        int srow = (bs % NS) * 16 + t;    // (s, o)
        int col  = (bs / NS) * 32 + c;    // (b, c)
        psum[srow * 256 + col] = a;
        psq [srow * 256 + col] = b;
    }
}

// ---------------------------------------------------------------------------
// Kernel 3: reduce BN partials -> scale/shift per (s,o). 384 WGs of 256.
// ---------------------------------------------------------------------------
__global__ __launch_bounds__(256) void k_bnstat(const float* __restrict__ psum,
                                                const float* __restrict__ psq,
                                                const float* __restrict__ gamma,
                                                const float* __restrict__ beta,
                                                float* __restrict__ scale,
                                                float* __restrict__ shift) {
    __shared__ float l1[4], l2[4];
    int row = blockIdx.x;
    int t = threadIdx.x;
    float s = psum[row * 256 + t], q = psq[row * 256 + t];
    for (int off = 32; off; off >>= 1) {
        s += __shfl_down(s, off);
        q += __shfl_down(q, off);
    }
    if ((t & 63) == 0) { l1[t >> 6] = s; l2[t >> 6] = q; }
    __syncthreads();
    if (t == 0) {
        s = l1[0] + l1[1] + l1[2] + l1[3];
        q = l2[0] + l2[1] + l2[2] + l2[3];
        float mean = s * (1.0f / BN_COUNT);
        float var  = q * (1.0f / BN_COUNT) - mean * mean;
        float inv  = rsqrtf(var + 1e-5f);
        int o = row & 15;
        float sc = gamma[o] * inv;
        scale[row] = sc;
        shift[row] = beta[o] - mean * sc;
    }
}

// ---------------------------------------------------------------------------
// Kernel 4: BN + relu + layer 3 + relu. WG per (bs, c2).
// W3[m] is a uniform loop index -> already on the scalar path.
// ---------------------------------------------------------------------------
__global__ __launch_bounds__(256) void k_layer3(const float* __restrict__ y2,
                                                const int* __restrict__ G3T,
                                                const float* __restrict__ scale,
                                                const float* __restrict__ shift,
                                                const float* __restrict__ W3,
                                                const float* __restrict__ b3,
                                                float* __restrict__ out) {
    __shared__ float zl[4096];
    int blk = blockIdx.x;                 // 3072 = 192 bs * 16 c2
    int c2 = blk & 15, bs = blk >> 4;
    int s = bs % NS;
    float sc = scale[s * 16 + c2], sh = shift[s * 16 + c2];
    const float* yb = y2 + ((size_t)bs * NC2 + c2) * NN;
    for (int j = threadIdx.x; j < 4096; j += 256)
        zl[j] = fmaxf(fmaf(yb[j], sc, sh), 0.f);
    __syncthreads();
    int r = threadIdx.x;
    const int* Gp = G3T + r;
    float acc = b3[0];
    for (int mc = 0; mc < 144; mc += 8) {
        int gs[8];
#pragma unroll
        for (int j = 0; j < 8; j++) gs[j] = Gp[(mc + j) << 8];
#pragma unroll
        for (int j = 0; j < 8; j++) acc = fmaf(zl[gs[j]], W3[mc + j], acc);
    }
    out[(size_t)bs * NN + c2 * 256 + r] = fmaxf(acc, 0.f);
}

// ---------------------------------------------------------------------------
extern "C" void kernel_launch(void* const* d_in, const int* in_sizes, int n_in,
                              void* d_out, int out_size, void* d_ws, size_t ws_size,
                              hipStream_t stream) {
    const float* input = (const float*)d_in[0];
    const int*   neigh = (const int*)d_in[1];
    const float* W1    = (const float*)d_in[2];
    const float* b1    = (const float*)d_in[3];
    const float* W2    = (const float*)d_in[4];
    const float* b2    = (const float*)d_in[5];
    const float* gamma = (const float*)d_in[6];
    const float* beta  = (const float*)d_in[7];
    const float* W3    = (const float*)d_in[8];
    const float* b3    = (const float*)d_in[9];
    float* out = (float*)d_out;

    // Workspace layout (bytes), total ~152.1 MB
    char* ws = (char*)d_ws;
    int*   G2T   = (int*)  (ws);                      // 147456
    int*   G3T   = (int*)  (ws + 147456);             // 147456
    float* W2T   = (float*)(ws + 294912);             // 18432
    float* h     = (float*)(ws + 313344);             // 100663296
    float* y2    = (float*)(ws + 100976640);          // 50331648
    float* psum  = (float*)(ws + 151308288);          // 393216
    float* psq   = (float*)(ws + 151701504);          // 393216
    float* scale = (float*)(ws + 152094720);          // 1536
    float* shift = (float*)(ws + 152096256);          // 1536

    k_tables<<<306, 256, 0, stream>>>(neigh, G2T, G3T, W2, W2T);
    k_layer1<<<1536, 256, 0, stream>>>(input, W1, b1, h);
    k_layer2<<<6144, 256, 0, stream>>>(h, G2T, W2T, b2, y2, psum, psq);
    k_bnstat<<<384, 256, 0, stream>>>(psum, psq, gamma, beta, scale, shift);
    k_layer3<<<3072, 256, 0, stream>>>(y2, G3T, scale, shift, W3, b3, out);
}

// Round 3
// 256.975 us; speedup vs baseline: 2.2465x; 1.0380x over previous
//
#include <hip/hip_runtime.h>
#include <hip/hip_bf16.h>

// Problem constants (B=8,S=24,N=4096,K=9,C1=32,C2=16)
#define NB 8
#define NS 24
#define NN 4096
#define NC1 32
#define NC2 16
#define BN_COUNT 32768.0f    // B*N elements per (s,o) for batchnorm

typedef float f32x2 __attribute__((ext_vector_type(2)));

// acc += v * w  (packed 2x fp32). w on the SCALAR path (wave-uniform weights),
// v is a VGPR pair of two gathered values, acc.lo/.hi accumulate even/odd taps.
__device__ __forceinline__ void pkfma(f32x2& acc, f32x2 v, f32x2 w) {
    asm("v_pk_fma_f32 %0, %1, %2, %0" : "+v"(acc) : "v"(v), "s"(w));
}

// ---------------------------------------------------------------------------
// Kernel 0: build gather tables (int4-quad layouts) + paired weight table.
//  G2Q: int4 entries, e = m4*128 + r (m4<72,r<128); element jj: m=m4*4+jj,
//       rem=r*288+m, val=neigh[(rem&4095)*9 + (rem>>12)]
//  G3Q: int4 entries, e = m4*256 + r (m4<36,r<256); rem=r*144+m
//  W2P: float2 pairs [m2][o] (m2<144,o<16) = {W2[o][2m2], W2[o][2m2+1]}
// ---------------------------------------------------------------------------
__global__ void k_tables(const int* __restrict__ neigh,
                         int* __restrict__ G2Q, int* __restrict__ G3Q,
                         const float* __restrict__ W2, float* __restrict__ W2P) {
    int j = blockIdx.x * 256 + threadIdx.x;          // grid = 306*256 = 78336
    if (j < 36864) {                                 // G2Q
        int e = j >> 2, jj = j & 3;
        int m4 = e >> 7, r = e & 127;
        int m = m4 * 4 + jj;
        int rem = r * 288 + m;
        G2Q[j] = neigh[(rem & 4095) * 9 + (rem >> 12)];
    } else if (j < 73728) {                          // G3Q
        int t = j - 36864;
        int e = t >> 2, jj = t & 3;
        int m4 = e >> 8, r = e & 255;
        int m = m4 * 4 + jj;
        int rem = r * 144 + m;
        G3Q[t] = neigh[(rem & 4095) * 9 + (rem >> 12)];
    } else {                                         // W2P (4608 floats)
        int t = j - 73728;
        int w = t >> 1, hh = t & 1;
        int m2 = w >> 4, o = w & 15;
        W2P[w * 2 + hh] = W2[o * 288 + m2 * 2 + hh];
    }
}

// ---------------------------------------------------------------------------
// Kernel 1: layer 1 -> bf16 h.  h[bs][c][n] = relu(b1[c] + sum_m W1[c,m]*F[..])
// ---------------------------------------------------------------------------
__global__ __launch_bounds__(256) void k_layer1(const float* __restrict__ input,
                                                const float* __restrict__ W1,
                                                const float* __restrict__ b1,
                                                __hip_bfloat16* __restrict__ h) {
    __shared__ float F[4608];
    int blk = blockIdx.x;                 // 1536 = 192 bs * 8 tiles
    int tile = blk & 7, bs = blk >> 3;
    const float* A = input + (size_t)bs * 36864;
    int I0 = tile * 4608;
    for (int j = threadIdx.x; j < 4608; j += 256) {
        int idx = I0 + j;
        int n = idx & 4095, k = idx >> 12;
        F[j] = A[n * 9 + k];
    }
    __syncthreads();
    __hip_bfloat16* hb = h + (size_t)bs * (NC1 * NN);
    for (int lp = threadIdx.x; lp < 512; lp += 256) {
        float v[9];
#pragma unroll
        for (int m = 0; m < 9; m++) v[m] = F[lp * 9 + m];
        int p = tile * 512 + lp;
#pragma unroll 4
        for (int c = 0; c < 32; c++) {
            float acc = b1[c];
#pragma unroll
            for (int m = 0; m < 9; m++) acc = fmaf(v[m], W1[c * 9 + m], acc);
            hb[c * NN + p] = __float2bfloat16(fmaxf(acc, 0.f));
        }
    }
}

// ---------------------------------------------------------------------------
// Kernel 2: layer 2 + BN partial stats. WG per (bs, c). Gather via LDS (fp32
// copy of the bf16 h-slice), weights via scalar-path float2 pairs, math via
// v_pk_fma_f32 (even taps in .lo, odd taps in .hi -> one add at the end).
// ---------------------------------------------------------------------------
__global__ __launch_bounds__(256) void k_layer2(const __hip_bfloat16* __restrict__ h,
                                                const int4* __restrict__ G2Q,
                                                const f32x2* __restrict__ W2P,
                                                const float* __restrict__ b2,
                                                __hip_bfloat16* __restrict__ y2,
                                                float* __restrict__ psum,
                                                float* __restrict__ psq) {
    __shared__ __align__(16) float hl[4096];
    __shared__ float red[128 * 16];
    __shared__ float wred[64];
    int blk = blockIdx.x;                 // 6144 = 192 bs * 32 c
    int c = blk & 31, bs = blk >> 5;
    const __hip_bfloat162* hb2 =
        (const __hip_bfloat162*)(h + ((size_t)bs * NC1 + c) * NN);
    float2* hl2 = (float2*)hl;
    for (int j = threadIdx.x; j < 2048; j += 256) {
        float2 f = __bfloat1622float2(hb2[j]);
        hl2[j] = f;                       // ds_write_b64, conflict-free
    }
    __syncthreads();

    int t = threadIdx.x;
    int r = t & 127, half = t >> 7;
    // quad base: waves 0,1 -> m-quads [0,36); waves 2,3 -> [36,72)
    int mq0 = __builtin_amdgcn_readfirstlane(half * 36);

    f32x2 accp[16];
#pragma unroll
    for (int o = 0; o < 16; o++) accp[o] = (f32x2){0.f, 0.f};

    const int4* Gp = G2Q + r;             // entries at m4*128 + r
    for (int mc = 0; mc < 36; mc += 2) {  // 2 quads = 8 taps per chunk
        int4 qa = Gp[(mq0 + mc) * 128];
        int4 qb = Gp[(mq0 + mc + 1) * 128];
        float v0 = hl[qa.x], v1 = hl[qa.y], v2 = hl[qa.z], v3 = hl[qa.w];
        float v4 = hl[qb.x], v5 = hl[qb.y], v6 = hl[qb.z], v7 = hl[qb.w];
        f32x2 p01 = {v0, v1}, p23 = {v2, v3}, p45 = {v4, v5}, p67 = {v6, v7};
        const f32x2* wp = W2P + (size_t)(mq0 + mc) * 32;  // m2 = (mq0+mc)*2
#pragma unroll
        for (int o = 0; o < 16; o++) {
            pkfma(accp[o], p01, wp[o]);
            pkfma(accp[o], p23, wp[16 + o]);
            pkfma(accp[o], p45, wp[32 + o]);
            pkfma(accp[o], p67, wp[48 + o]);
        }
    }

    if (half == 1) {
#pragma unroll
        for (int o = 0; o < 16; o++) red[r * 16 + o] = accp[o].x + accp[o].y;
    }
    __syncthreads();

    if (half == 0) {
        float acc[16], s1[16], s2[16];
#pragma unroll
        for (int o = 0; o < 16; o++) {
            acc[o] = accp[o].x + accp[o].y + red[r * 16 + o] + b2[o];
            s1[o] = acc[o];
            s2[o] = acc[o] * acc[o];
        }
        // y2[bs][o][n], n = c*128 + r  (coalesced per o)
        __hip_bfloat16* yb = y2 + (size_t)bs * NC2 * NN + (c * 128 + r);
#pragma unroll
        for (int o = 0; o < 16; o++) yb[o * NN] = __float2bfloat16(acc[o]);

        // wave reduction over 64 lanes (waves 0 and 1 hold half==0)
#pragma unroll
        for (int o = 0; o < 16; o++) {
            for (int off = 32; off; off >>= 1) {
                s1[o] += __shfl_down(s1[o], off);
                s2[o] += __shfl_down(s2[o], off);
            }
        }
        if ((t & 63) == 0) {
            int w = t >> 6;  // 0 or 1
#pragma unroll
            for (int o = 0; o < 16; o++) {
                wred[w * 16 + o]      = s1[o];
                wred[32 + w * 16 + o] = s2[o];
            }
        }
    }
    __syncthreads();
    if (t < 16) {
        float a = wred[t] + wred[16 + t];
        float b = wred[32 + t] + wred[48 + t];
        int srow = (bs % NS) * 16 + t;    // (s, o)
        int col  = (bs / NS) * 32 + c;    // (b, c)
        psum[srow * 256 + col] = a;
        psq [srow * 256 + col] = b;
    }
}

// ---------------------------------------------------------------------------
// Kernel 3: reduce BN partials -> scale/shift per (s,o). 384 WGs of 256.
// ---------------------------------------------------------------------------
__global__ __launch_bounds__(256) void k_bnstat(const float* __restrict__ psum,
                                                const float* __restrict__ psq,
                                                const float* __restrict__ gamma,
                                                const float* __restrict__ beta,
                                                float* __restrict__ scale,
                                                float* __restrict__ shift) {
    __shared__ float l1[4], l2[4];
    int row = blockIdx.x;
    int t = threadIdx.x;
    float s = psum[row * 256 + t], q = psq[row * 256 + t];
    for (int off = 32; off; off >>= 1) {
        s += __shfl_down(s, off);
        q += __shfl_down(q, off);
    }
    if ((t & 63) == 0) { l1[t >> 6] = s; l2[t >> 6] = q; }
    __syncthreads();
    if (t == 0) {
        s = l1[0] + l1[1] + l1[2] + l1[3];
        q = l2[0] + l2[1] + l2[2] + l2[3];
        float mean = s * (1.0f / BN_COUNT);
        float var  = q * (1.0f / BN_COUNT) - mean * mean;
        float inv  = rsqrtf(var + 1e-5f);
        int o = row & 15;
        float sc = gamma[o] * inv;
        scale[row] = sc;
        shift[row] = beta[o] - mean * sc;
    }
}

// ---------------------------------------------------------------------------
// Kernel 4: BN + relu + layer 3 + relu. WG per (bs, c2). Paired pk_fma too.
// ---------------------------------------------------------------------------
__global__ __launch_bounds__(256) void k_layer3(const __hip_bfloat16* __restrict__ y2,
                                                const int4* __restrict__ G3Q,
                                                const float* __restrict__ scale,
                                                const float* __restrict__ shift,
                                                const float* __restrict__ W3,
                                                const float* __restrict__ b3,
                                                float* __restrict__ out) {
    __shared__ __align__(16) float zl[4096];
    int blk = blockIdx.x;                 // 3072 = 192 bs * 16 c2
    int c2 = blk & 15, bs = blk >> 4;
    int s = bs % NS;
    float sc = scale[s * 16 + c2], sh = shift[s * 16 + c2];
    const __hip_bfloat162* yb2 =
        (const __hip_bfloat162*)(y2 + ((size_t)bs * NC2 + c2) * NN);
    float2* zl2 = (float2*)zl;
    for (int j = threadIdx.x; j < 2048; j += 256) {
        float2 f = __bfloat1622float2(yb2[j]);
        f.x = fmaxf(fmaf(f.x, sc, sh), 0.f);
        f.y = fmaxf(fmaf(f.y, sc, sh), 0.f);
        zl2[j] = f;
    }
    __syncthreads();
    int r = threadIdx.x;
    const int4* Gp = G3Q + r;             // entries at m4*256 + r
    const f32x2* W3P = (const f32x2*)W3;  // pairs m2 = 0..71
    f32x2 accp = {b3[0], 0.f};
    for (int mc = 0; mc < 36; mc += 2) {
        int4 qa = Gp[mc * 256];
        int4 qb = Gp[(mc + 1) * 256];
        f32x2 p01 = {zl[qa.x], zl[qa.y]}, p23 = {zl[qa.z], zl[qa.w]};
        f32x2 p45 = {zl[qb.x], zl[qb.y]}, p67 = {zl[qb.z], zl[qb.w]};
        pkfma(accp, p01, W3P[mc * 2 + 0]);
        pkfma(accp, p23, W3P[mc * 2 + 1]);
        pkfma(accp, p45, W3P[mc * 2 + 2]);
        pkfma(accp, p67, W3P[mc * 2 + 3]);
    }
    out[(size_t)bs * NN + c2 * 256 + r] = fmaxf(accp.x + accp.y, 0.f);
}

// ---------------------------------------------------------------------------
extern "C" void kernel_launch(void* const* d_in, const int* in_sizes, int n_in,
                              void* d_out, int out_size, void* d_ws, size_t ws_size,
                              hipStream_t stream) {
    const float* input = (const float*)d_in[0];
    const int*   neigh = (const int*)d_in[1];
    const float* W1    = (const float*)d_in[2];
    const float* b1    = (const float*)d_in[3];
    const float* W2    = (const float*)d_in[4];
    const float* b2    = (const float*)d_in[5];
    const float* gamma = (const float*)d_in[6];
    const float* beta  = (const float*)d_in[7];
    const float* W3    = (const float*)d_in[8];
    const float* b3    = (const float*)d_in[9];
    float* out = (float*)d_out;

    // Workspace layout (bytes), total ~76.6 MB (all offsets 16B-aligned)
    char* ws = (char*)d_ws;
    int*            G2Q   = (int*)            (ws);             // 147456
    int*            G3Q   = (int*)            (ws + 147456);    // 147456
    float*          W2P   = (float*)          (ws + 294912);    // 18432
    __hip_bfloat16* h     = (__hip_bfloat16*) (ws + 313344);    // 50331648
    __hip_bfloat16* y2    = (__hip_bfloat16*) (ws + 50644992);  // 25165824
    float*          psum  = (float*)          (ws + 75810816);  // 393216
    float*          psq   = (float*)          (ws + 76204032);  // 393216
    float*          scale = (float*)          (ws + 76597248);  // 1536
    float*          shift = (float*)          (ws + 76598784);  // 1536

    k_tables<<<306, 256, 0, stream>>>(neigh, G2Q, G3Q, W2, W2P);
    k_layer1<<<1536, 256, 0, stream>>>(input, W1, b1, h);
    k_layer2<<<6144, 256, 0, stream>>>(h, (const int4*)G2Q, (const f32x2*)W2P,
                                       b2, y2, psum, psq);
    k_bnstat<<<384, 256, 0, stream>>>(psum, psq, gamma, beta, scale, shift);
    k_layer3<<<3072, 256, 0, stream>>>(y2, (const int4*)G3Q, scale, shift,
                                       W3, b3, out);
}

// Round 4
// 184.970 us; speedup vs baseline: 3.1210x; 1.3893x over previous
//
#include <hip/hip_runtime.h>
#include <hip/hip_bf16.h>

// Problem constants (B=8,S=24,N=4096,K=9,C1=32,C2=16)
#define NB 8
#define NS 24
#define NN 4096
#define NC1 32
#define NC2 16
#define BN_COUNT 32768.0f    // B*N elements per (s,o) for batchnorm

typedef float f32x4 __attribute__((ext_vector_type(4)));
typedef short bf16x8 __attribute__((ext_vector_type(8)));
union U8 { int4 i; bf16x8 b; };

#define PERM_LO 0x05040100u   // {lo16(s1), lo16(s0)} -> dst = {s1.lo, s0.lo<<16}? see below
#define PERM_HI 0x07060302u

// __builtin_amdgcn_perm(hi, lo, sel): data bytes 0-3 = lo, 4-7 = hi.
// PERM_LO -> dst = { lo.b0, lo.b1, hi.b0, hi.b1 } = {lo16(lo), lo16(hi)}
// PERM_HI -> dst = { lo.b2, lo.b3, hi.b2, hi.b3 } = {hi16(lo), hi16(hi)}

// ---------------------------------------------------------------------------
// Kernel 0: build tables.
//  G2M[((t*9+kb)*64+l)*8+j]: MFMA-lane-ordered gather indices for layer 2.
//     r = t*16+(l&15), k = kb*32+(l>>4)*8+j, rem = r*288+k,
//     val = neigh[(rem&4095)*9 + (rem>>12)]
//  G3Q: int4 quads, entry e = m4*256+r: rem = r*144+(m4*4+jj)
//  W2B[kb*512 + l*8 + j]: bf16 B-fragments: B[k][o], k as above, o = l&15
// ---------------------------------------------------------------------------
__global__ void k_tables(const int* __restrict__ neigh,
                         int* __restrict__ G2M, int* __restrict__ G3Q,
                         const float* __restrict__ W2,
                         __hip_bfloat16* __restrict__ W2B) {
    int j = blockIdx.x * 256 + threadIdx.x;          // grid = 306*256 = 78336
    if (j < 36864) {                                 // G2M
        int j8 = j & 7;
        int tkbl = j >> 3;
        int l = tkbl & 63;
        int tkb = tkbl >> 6;                         // < 72
        int t = tkb / 9, kb = tkb - t * 9;
        int r = t * 16 + (l & 15);
        int k = kb * 32 + ((l >> 4) << 3) + j8;
        int rem = r * 288 + k;
        G2M[j] = neigh[(rem & 4095) * 9 + (rem >> 12)];
    } else if (j < 73728) {                          // G3Q
        int tt = j - 36864;
        int e = tt >> 2, jj = tt & 3;
        int m4 = e >> 8, r = e & 255;
        int m = m4 * 4 + jj;
        int rem = r * 144 + m;
        G3Q[tt] = neigh[(rem & 4095) * 9 + (rem >> 12)];
    } else {                                         // W2B (4608 bf16)
        int jj = j - 73728;
        int kb = jj >> 9;
        int rest = jj & 511;
        int l = rest >> 3, j8 = rest & 7;
        int o = l & 15;
        int k = kb * 32 + ((l >> 4) << 3) + j8;
        W2B[jj] = __float2bfloat16(W2[o * 288 + k]);
    }
}

// ---------------------------------------------------------------------------
// Kernel 1: layer 1 -> bf16 h.  h[bs][c][n] = relu(b1[c] + sum_m W1[c,m]*F[..])
// ---------------------------------------------------------------------------
__global__ __launch_bounds__(256) void k_layer1(const float* __restrict__ input,
                                                const float* __restrict__ W1,
                                                const float* __restrict__ b1,
                                                __hip_bfloat16* __restrict__ h) {
    __shared__ float F[4608];
    int blk = blockIdx.x;                 // 1536 = 192 bs * 8 tiles
    int tile = blk & 7, bs = blk >> 3;
    const float* A = input + (size_t)bs * 36864;
    int I0 = tile * 4608;
    for (int j = threadIdx.x; j < 4608; j += 256) {
        int idx = I0 + j;
        int n = idx & 4095, k = idx >> 12;
        F[j] = A[n * 9 + k];
    }
    __syncthreads();
    __hip_bfloat16* hb = h + (size_t)bs * (NC1 * NN);
    for (int lp = threadIdx.x; lp < 512; lp += 256) {
        float v[9];
#pragma unroll
        for (int m = 0; m < 9; m++) v[m] = F[lp * 9 + m];
        int p = tile * 512 + lp;
#pragma unroll 4
        for (int c = 0; c < 32; c++) {
            float acc = b1[c];
#pragma unroll
            for (int m = 0; m < 9; m++) acc = fmaf(v[m], W1[c * 9 + m], acc);
            hb[c * NN + p] = __float2bfloat16(fmaxf(acc, 0.f));
        }
    }
}

// ---------------------------------------------------------------------------
// Kernel 2: layer 2 via MFMA. WG per (bs, channel-pair). LDS holds packed
// {h_c0, h_c1} bf16x2 per node -> one ds_read_b32 gather serves 2 channels.
// Gathered dwords are perm-split into per-channel bf16 A-frags; W2 is
// pre-baked in B-frag lane order; 2 MFMAs per (tile, kb).
// Deterministic per-block BN partials via shfl + LDS.
// ---------------------------------------------------------------------------
__global__ __launch_bounds__(256) void k_layer2(const __hip_bfloat16* __restrict__ h,
                                                const int4* __restrict__ G2M4,
                                                const int4* __restrict__ W2B4,
                                                const float* __restrict__ b2,
                                                __hip_bfloat16* __restrict__ y2,
                                                float* __restrict__ psum,
                                                float* __restrict__ psq) {
    __shared__ __align__(16) unsigned int hl[4096];
    __shared__ float4 wsum[4][16];
    int blk = blockIdx.x;                 // 3072 = 192 bs * 16 cpairs
    int cp = blk & 15, bs = blk >> 4;
    int c0 = cp * 2;
    const unsigned int* hb0 = (const unsigned int*)(h + ((size_t)bs * NC1 + c0) * NN);
    const unsigned int* hb1 = (const unsigned int*)(h + ((size_t)bs * NC1 + c0 + 1) * NN);
    uint2* hl2 = (uint2*)hl;
    for (int j = threadIdx.x; j < 2048; j += 256) {
        unsigned int u0 = hb0[j], u1 = hb1[j];
        uint2 p;
        p.x = __builtin_amdgcn_perm(u1, u0, PERM_LO);  // node 2j:   {c0,c1}
        p.y = __builtin_amdgcn_perm(u1, u0, PERM_HI);  // node 2j+1: {c0,c1}
        hl2[j] = p;
    }
    __syncthreads();

    int tid = threadIdx.x;
    int l = tid & 63, w = tid >> 6;
    int o = l & 15, q = l >> 4;

    // B-fragments for all 9 K-blocks (36 VGPRs)
    U8 bfrag[9];
#pragma unroll
    for (int kb = 0; kb < 9; kb++) bfrag[kb].i = W2B4[kb * 64 + l];
    float bb = b2[o];

    float s1c0 = 0.f, s2c0 = 0.f, s1c1 = 0.f, s2c1 = 0.f;

    for (int tt = 0; tt < 2; tt++) {
        int t = w * 2 + tt;
        f32x4 ac0 = {0.f, 0.f, 0.f, 0.f};
        f32x4 ac1 = {0.f, 0.f, 0.f, 0.f};
        const int4* gp = G2M4 + (size_t)(t * 9) * 128 + l * 2;
#pragma unroll
        for (int kb = 0; kb < 9; kb++) {
            int4 ia = gp[kb * 128];
            int4 ib = gp[kb * 128 + 1];
            unsigned int d0 = hl[ia.x], d1 = hl[ia.y], d2 = hl[ia.z], d3 = hl[ia.w];
            unsigned int d4 = hl[ib.x], d5 = hl[ib.y], d6 = hl[ib.z], d7 = hl[ib.w];
            U8 a0, a1;
            a0.i.x = __builtin_amdgcn_perm(d1, d0, PERM_LO);
            a0.i.y = __builtin_amdgcn_perm(d3, d2, PERM_LO);
            a0.i.z = __builtin_amdgcn_perm(d5, d4, PERM_LO);
            a0.i.w = __builtin_amdgcn_perm(d7, d6, PERM_LO);
            a1.i.x = __builtin_amdgcn_perm(d1, d0, PERM_HI);
            a1.i.y = __builtin_amdgcn_perm(d3, d2, PERM_HI);
            a1.i.z = __builtin_amdgcn_perm(d5, d4, PERM_HI);
            a1.i.w = __builtin_amdgcn_perm(d7, d6, PERM_HI);
            ac0 = __builtin_amdgcn_mfma_f32_16x16x32_bf16(a0.b, bfrag[kb].b, ac0, 0, 0, 0);
            ac1 = __builtin_amdgcn_mfma_f32_16x16x32_bf16(a1.b, bfrag[kb].b, ac1, 0, 0, 0);
        }
        // C layout: col(o) = lane&15, row = (lane>>4)*4 + reg
        __hip_bfloat16* yb = y2 + (size_t)bs * (NC2 * NN) + o * NN;
        int rbase = t * 16 + q * 4;
#pragma unroll
        for (int i = 0; i < 4; i++) {
            float v0 = ac0[i] + bb;
            float v1 = ac1[i] + bb;
            int n0 = c0 * 128 + rbase + i;      // channel c0 point
            yb[n0]       = __float2bfloat16(v0);
            yb[n0 + 128] = __float2bfloat16(v1); // channel c1 point
            s1c0 += v0; s2c0 += v0 * v0;
            s1c1 += v1; s2c1 += v1 * v1;
        }
    }

    // reduce stats across lanes with same o (xor 16, 32)
    s1c0 += __shfl_xor(s1c0, 16); s1c0 += __shfl_xor(s1c0, 32);
    s2c0 += __shfl_xor(s2c0, 16); s2c0 += __shfl_xor(s2c0, 32);
    s1c1 += __shfl_xor(s1c1, 16); s1c1 += __shfl_xor(s1c1, 32);
    s2c1 += __shfl_xor(s2c1, 16); s2c1 += __shfl_xor(s2c1, 32);
    if (l < 16) wsum[w][l] = make_float4(s1c0, s2c0, s1c1, s2c1);
    __syncthreads();
    if (tid < 32) {
        int ch = tid >> 4, oo = tid & 15;
        float a = 0.f, b = 0.f;
#pragma unroll
        for (int ww = 0; ww < 4; ww++) {
            float4 v = wsum[ww][oo];
            a += ch ? v.z : v.x;
            b += ch ? v.w : v.y;
        }
        int s_idx = bs % NS, b_idx = bs / NS;
        int srow = s_idx * 16 + oo;
        int col  = b_idx * 32 + (c0 + ch);
        psum[srow * 256 + col] = a;
        psq [srow * 256 + col] = b;
    }
}

// ---------------------------------------------------------------------------
// Kernel 3: reduce BN partials -> scale/shift per (s,o). 384 WGs of 256.
// ---------------------------------------------------------------------------
__global__ __launch_bounds__(256) void k_bnstat(const float* __restrict__ psum,
                                                const float* __restrict__ psq,
                                                const float* __restrict__ gamma,
                                                const float* __restrict__ beta,
                                                float* __restrict__ scale,
                                                float* __restrict__ shift) {
    __shared__ float l1[4], l2[4];
    int row = blockIdx.x;
    int t = threadIdx.x;
    float s = psum[row * 256 + t], q = psq[row * 256 + t];
    for (int off = 32; off; off >>= 1) {
        s += __shfl_down(s, off);
        q += __shfl_down(q, off);
    }
    if ((t & 63) == 0) { l1[t >> 6] = s; l2[t >> 6] = q; }
    __syncthreads();
    if (t == 0) {
        s = l1[0] + l1[1] + l1[2] + l1[3];
        q = l2[0] + l2[1] + l2[2] + l2[3];
        float mean = s * (1.0f / BN_COUNT);
        float var  = q * (1.0f / BN_COUNT) - mean * mean;
        float inv  = rsqrtf(var + 1e-5f);
        int o = row & 15;
        float sc = gamma[o] * inv;
        scale[row] = sc;
        shift[row] = beta[o] - mean * sc;
    }
}

// ---------------------------------------------------------------------------
// Kernel 4: BN + relu + layer 3 + relu. WG per (bs, c2-PAIR): LDS packs
// {z_c0, z_c1} bf16x2 per node -> one gather serves 2 output points.
// bf16->fp32 decode: lo = d<<16, hi = d & 0xffff0000.
// ---------------------------------------------------------------------------
__global__ __launch_bounds__(256) void k_layer3(const __hip_bfloat16* __restrict__ y2,
                                                const int* __restrict__ G3Q,
                                                const float* __restrict__ scale,
                                                const float* __restrict__ shift,
                                                const float* __restrict__ W3,
                                                const float* __restrict__ b3,
                                                float* __restrict__ out) {
    __shared__ __align__(16) unsigned int zl[4096];
    int blk = blockIdx.x;                 // 1536 = 192 bs * 8 c2-pairs
    int cpp = blk & 7, bs = blk >> 3;
    int c0 = cpp * 2;
    int s = bs % NS;
    float sc0 = scale[s * 16 + c0],     sh0 = shift[s * 16 + c0];
    float sc1 = scale[s * 16 + c0 + 1], sh1 = shift[s * 16 + c0 + 1];
    const unsigned int* yb0 = (const unsigned int*)(y2 + ((size_t)bs * NC2 + c0) * NN);
    const unsigned int* yb1 = (const unsigned int*)(y2 + ((size_t)bs * NC2 + c0 + 1) * NN);
    uint2* zl2 = (uint2*)zl;
    for (int j = threadIdx.x; j < 2048; j += 256) {
        unsigned int u0 = yb0[j], u1 = yb1[j];
        float a0 = fmaxf(fmaf(__uint_as_float(u0 << 16),          sc0, sh0), 0.f); // c0, n=2j
        float a1 = fmaxf(fmaf(__uint_as_float(u0 & 0xffff0000u),  sc0, sh0), 0.f); // c0, n=2j+1
        float b0 = fmaxf(fmaf(__uint_as_float(u1 << 16),          sc1, sh1), 0.f); // c1, n=2j
        float b1 = fmaxf(fmaf(__uint_as_float(u1 & 0xffff0000u),  sc1, sh1), 0.f); // c1, n=2j+1
        __hip_bfloat16 ba0 = __float2bfloat16(a0), bb0 = __float2bfloat16(b0);
        __hip_bfloat16 ba1 = __float2bfloat16(a1), bb1 = __float2bfloat16(b1);
        uint2 p;
        p.x = (unsigned int)*(unsigned short*)&ba0 | ((unsigned int)*(unsigned short*)&bb0 << 16);
        p.y = (unsigned int)*(unsigned short*)&ba1 | ((unsigned int)*(unsigned short*)&bb1 << 16);
        zl2[j] = p;
    }
    __syncthreads();
    int r = threadIdx.x;
    const int4* gq = (const int4*)G3Q;
    float acc0 = b3[0], acc1 = b3[0];
    for (int m4 = 0; m4 < 36; m4 += 2) {
        int4 qa = gq[m4 * 256 + r];
        int4 qb = gq[(m4 + 1) * 256 + r];
        unsigned int d0 = zl[qa.x], d1 = zl[qa.y], d2 = zl[qa.z], d3 = zl[qa.w];
        unsigned int d4 = zl[qb.x], d5 = zl[qb.y], d6 = zl[qb.z], d7 = zl[qb.w];
        unsigned int dd[8] = {d0, d1, d2, d3, d4, d5, d6, d7};
#pragma unroll
        for (int jj = 0; jj < 8; jj++) {
            float wv = W3[m4 * 4 + jj];           // wave-uniform -> scalar
            acc0 = fmaf(__uint_as_float(dd[jj] << 16),         wv, acc0);
            acc1 = fmaf(__uint_as_float(dd[jj] & 0xffff0000u), wv, acc1);
        }
    }
    float* ob = out + (size_t)bs * NN + c0 * 256 + r;
    ob[0]   = fmaxf(acc0, 0.f);
    ob[256] = fmaxf(acc1, 0.f);
}

// ---------------------------------------------------------------------------
extern "C" void kernel_launch(void* const* d_in, const int* in_sizes, int n_in,
                              void* d_out, int out_size, void* d_ws, size_t ws_size,
                              hipStream_t stream) {
    const float* input = (const float*)d_in[0];
    const int*   neigh = (const int*)d_in[1];
    const float* W1    = (const float*)d_in[2];
    const float* b1    = (const float*)d_in[3];
    const float* W2    = (const float*)d_in[4];
    const float* b2    = (const float*)d_in[5];
    const float* gamma = (const float*)d_in[6];
    const float* beta  = (const float*)d_in[7];
    const float* W3    = (const float*)d_in[8];
    const float* b3    = (const float*)d_in[9];
    float* out = (float*)d_out;

    // Workspace layout (bytes), total ~76.6 MB (all offsets 16B-aligned)
    char* ws = (char*)d_ws;
    int*            G2M   = (int*)            (ws);             // 147456
    int*            G3Q   = (int*)            (ws + 147456);    // 147456
    __hip_bfloat16* W2B   = (__hip_bfloat16*) (ws + 294912);    // 9216
    __hip_bfloat16* h     = (__hip_bfloat16*) (ws + 304128);    // 50331648
    __hip_bfloat16* y2    = (__hip_bfloat16*) (ws + 50635776);  // 25165824
    float*          psum  = (float*)          (ws + 75801600);  // 393216
    float*          psq   = (float*)          (ws + 76194816);  // 393216
    float*          scale = (float*)          (ws + 76588032);  // 1536
    float*          shift = (float*)          (ws + 76589568);  // 1536

    k_tables<<<306, 256, 0, stream>>>(neigh, G2M, G3Q, W2, W2B);
    k_layer1<<<1536, 256, 0, stream>>>(input, W1, b1, h);
    k_layer2<<<3072, 256, 0, stream>>>(h, (const int4*)G2M, (const int4*)W2B,
                                       b2, y2, psum, psq);
    k_bnstat<<<384, 256, 0, stream>>>(psum, psq, gamma, beta, scale, shift);
    k_layer3<<<1536, 256, 0, stream>>>(y2, G3Q, scale, shift, W3, b3, out);
}

// Round 5
// 161.806 us; speedup vs baseline: 3.5678x; 1.1432x over previous
//
#include <hip/hip_runtime.h>
#include <hip/hip_bf16.h>

// Problem constants (B=8,S=24,N=4096,K=9,C1=32,C2=16)
#define NB 8
#define NS 24
#define NN 4096
#define NC1 32
#define NC2 16
#define BN_COUNT 32768.0f    // B*N elements per (s,o) for batchnorm

typedef float f32x4 __attribute__((ext_vector_type(4)));
typedef short bf16x8 __attribute__((ext_vector_type(8)));
union U8 { int4 i; bf16x8 b; };

#define PERM_LO 0x05040100u
#define PERM_HI 0x07060302u

// __builtin_amdgcn_perm(hi, lo, sel): data bytes 0-3 = lo, 4-7 = hi.
// PERM_LO -> {lo16(lo), lo16(hi)} ; PERM_HI -> {hi16(lo), hi16(hi)}

// ---------------------------------------------------------------------------
// Kernel 0: build tables.
//  G2M[((t*9+kb)*64+l)*8+j]: MFMA-lane-ordered gather indices for layer 2.
//     r = t*16+(l&15), k = kb*32+(l>>4)*8+j, rem = r*288+k,
//     val = neigh[(rem&4095)*9 + (rem>>12)]
//  G3Q: int4 quads, entry e = m4*256+r: rem = r*144+(m4*4+jj)
//  W2B[kb*512 + l*8 + j]: bf16 B-fragments: B[k][o], k as above, o = l&15
// ---------------------------------------------------------------------------
__global__ void k_tables(const int* __restrict__ neigh,
                         int* __restrict__ G2M, int* __restrict__ G3Q,
                         const float* __restrict__ W2,
                         __hip_bfloat16* __restrict__ W2B) {
    int j = blockIdx.x * 256 + threadIdx.x;          // grid = 306*256 = 78336
    if (j < 36864) {                                 // G2M
        int j8 = j & 7;
        int tkbl = j >> 3;
        int l = tkbl & 63;
        int tkb = tkbl >> 6;                         // < 72
        int t = tkb / 9, kb = tkb - t * 9;
        int r = t * 16 + (l & 15);
        int k = kb * 32 + ((l >> 4) << 3) + j8;
        int rem = r * 288 + k;
        G2M[j] = neigh[(rem & 4095) * 9 + (rem >> 12)];
    } else if (j < 73728) {                          // G3Q
        int tt = j - 36864;
        int e = tt >> 2, jj = tt & 3;
        int m4 = e >> 8, r = e & 255;
        int m = m4 * 4 + jj;
        int rem = r * 144 + m;
        G3Q[tt] = neigh[(rem & 4095) * 9 + (rem >> 12)];
    } else {                                         // W2B (4608 bf16)
        int jj = j - 73728;
        int kb = jj >> 9;
        int rest = jj & 511;
        int l = rest >> 3, j8 = rest & 7;
        int o = l & 15;
        int k = kb * 32 + ((l >> 4) << 3) + j8;
        W2B[jj] = __float2bfloat16(W2[o * 288 + k]);
    }
}

// ---------------------------------------------------------------------------
// Kernel 1: layer 1 -> bf16 h. Re-tiled by INPUT n-window: WG (bs, w) stages
// the contiguous range A[n0*9 .. n0*9+4680) (n in [n0,n0+520), all k) fully
// coalesced -- every fetched byte is used exactly once (fixes the 4.4x
// over-fetch of idx-space tiling). Points whose first tap lands in
// [n0,n0+512) are 9 intervals of ~57 per k; tap m reads win[(nf-n0)*9+k+9m]
// (stride 81 dwords across lanes: 81%32=17, coprime -> conflict-free).
// Points with nf>4087 wrap into k+1 at n<8 -> staged "corner" block.
// ---------------------------------------------------------------------------
__global__ __launch_bounds__(256) void k_layer1(const float* __restrict__ input,
                                                const float* __restrict__ W1,
                                                const float* __restrict__ b1,
                                                __hip_bfloat16* __restrict__ h) {
    __shared__ __align__(16) float win[4680];
    __shared__ __align__(16) float corner[72];
    int blk = blockIdx.x;                 // 1536 = 192 bs * 8 windows
    int w = blk & 7, bs = blk >> 3;
    int n0 = w * 512;
    const float* A = input + (size_t)bs * 36864;
    int base = n0 * 9;                    // 4608*w, 16B-aligned
    int cnt4 = min(4680, 36864 - base) >> 2;   // 1170 (or 1152 for w=7)
    const float4* A4 = (const float4*)(A + base);
    float4* win4 = (float4*)win;
    for (int j = threadIdx.x; j < cnt4; j += 256) win4[j] = A4[j];
    if (threadIdx.x < 18) ((float4*)corner)[threadIdx.x] = ((const float4*)A)[threadIdx.x];
    __syncthreads();

    __hip_bfloat16* hb = h + (size_t)bs * (NC1 * NN);
    for (int i = threadIdx.x; i < 522; i += 256) {
        int j = i / 58, off = i - j * 58;           // k-interval, offset
        int x = j * 4096 + n0;
        int pstart = (x + 8) / 9;                   // ceil(x/9)
        int pend   = (x + 520) / 9;                 // ceil((x+512)/9)
        int p = pstart + off;
        if (p >= pend) continue;
        int nf = (p * 9) & 4095;                    // first-tap n (k = j)
        float v[9];
        int wb = (nf - n0) * 9 + j;
        if (nf <= 4087) {                           // all 9 taps in window
#pragma unroll
            for (int m = 0; m < 9; m++) v[m] = win[wb + 9 * m];
        } else {                                    // tail wraps into k+1
            int nw = 4096 - nf;
#pragma unroll
            for (int m = 0; m < 9; m++)
                v[m] = (m < nw) ? win[wb + 9 * m]
                                : corner[(nf + m - 4096) * 9 + j + 1];
        }
#pragma unroll 4
        for (int c = 0; c < 32; c++) {
            float acc = b1[c];
#pragma unroll
            for (int m = 0; m < 9; m++) acc = fmaf(v[m], W1[c * 9 + m], acc);
            hb[c * NN + p] = __float2bfloat16(fmaxf(acc, 0.f));
        }
    }
}

// ---------------------------------------------------------------------------
// Kernel 2: layer 2 via MFMA. WG per (bs, channel-pair). LDS holds packed
// {h_c0, h_c1} bf16x2 per node -> one ds_read_b32 gather serves 2 channels.
// Gathered dwords are perm-split into per-channel bf16 A-frags; W2 is
// pre-baked in B-frag lane order; 2 MFMAs per (tile, kb).
// ---------------------------------------------------------------------------
__global__ __launch_bounds__(256) void k_layer2(const __hip_bfloat16* __restrict__ h,
                                                const int4* __restrict__ G2M4,
                                                const int4* __restrict__ W2B4,
                                                const float* __restrict__ b2,
                                                __hip_bfloat16* __restrict__ y2,
                                                float* __restrict__ psum,
                                                float* __restrict__ psq) {
    __shared__ __align__(16) unsigned int hl[4096];
    __shared__ float4 wsum[4][16];
    int blk = blockIdx.x;                 // 3072 = 192 bs * 16 cpairs
    int cp = blk & 15, bs = blk >> 4;
    int c0 = cp * 2;
    const unsigned int* hb0 = (const unsigned int*)(h + ((size_t)bs * NC1 + c0) * NN);
    const unsigned int* hb1 = (const unsigned int*)(h + ((size_t)bs * NC1 + c0 + 1) * NN);
    uint2* hl2 = (uint2*)hl;
    for (int j = threadIdx.x; j < 2048; j += 256) {
        unsigned int u0 = hb0[j], u1 = hb1[j];
        uint2 p;
        p.x = __builtin_amdgcn_perm(u1, u0, PERM_LO);  // node 2j:   {c0,c1}
        p.y = __builtin_amdgcn_perm(u1, u0, PERM_HI);  // node 2j+1: {c0,c1}
        hl2[j] = p;
    }
    __syncthreads();

    int tid = threadIdx.x;
    int l = tid & 63, w = tid >> 6;
    int o = l & 15, q = l >> 4;

    U8 bfrag[9];
#pragma unroll
    for (int kb = 0; kb < 9; kb++) bfrag[kb].i = W2B4[kb * 64 + l];
    float bb = b2[o];

    float s1c0 = 0.f, s2c0 = 0.f, s1c1 = 0.f, s2c1 = 0.f;

    for (int tt = 0; tt < 2; tt++) {
        int t = w * 2 + tt;
        f32x4 ac0 = {0.f, 0.f, 0.f, 0.f};
        f32x4 ac1 = {0.f, 0.f, 0.f, 0.f};
        const int4* gp = G2M4 + (size_t)(t * 9) * 128 + l * 2;
#pragma unroll
        for (int kb = 0; kb < 9; kb++) {
            int4 ia = gp[kb * 128];
            int4 ib = gp[kb * 128 + 1];
            unsigned int d0 = hl[ia.x], d1 = hl[ia.y], d2 = hl[ia.z], d3 = hl[ia.w];
            unsigned int d4 = hl[ib.x], d5 = hl[ib.y], d6 = hl[ib.z], d7 = hl[ib.w];
            U8 a0, a1;
            a0.i.x = __builtin_amdgcn_perm(d1, d0, PERM_LO);
            a0.i.y = __builtin_amdgcn_perm(d3, d2, PERM_LO);
            a0.i.z = __builtin_amdgcn_perm(d5, d4, PERM_LO);
            a0.i.w = __builtin_amdgcn_perm(d7, d6, PERM_LO);
            a1.i.x = __builtin_amdgcn_perm(d1, d0, PERM_HI);
            a1.i.y = __builtin_amdgcn_perm(d3, d2, PERM_HI);
            a1.i.z = __builtin_amdgcn_perm(d5, d4, PERM_HI);
            a1.i.w = __builtin_amdgcn_perm(d7, d6, PERM_HI);
            ac0 = __builtin_amdgcn_mfma_f32_16x16x32_bf16(a0.b, bfrag[kb].b, ac0, 0, 0, 0);
            ac1 = __builtin_amdgcn_mfma_f32_16x16x32_bf16(a1.b, bfrag[kb].b, ac1, 0, 0, 0);
        }
        // C layout: col(o) = lane&15, row = (lane>>4)*4 + reg
        __hip_bfloat16* yb = y2 + (size_t)bs * (NC2 * NN) + o * NN;
        int rbase = t * 16 + q * 4;
#pragma unroll
        for (int i = 0; i < 4; i++) {
            float v0 = ac0[i] + bb;
            float v1 = ac1[i] + bb;
            int n0 = c0 * 128 + rbase + i;
            yb[n0]       = __float2bfloat16(v0);
            yb[n0 + 128] = __float2bfloat16(v1);
            s1c0 += v0; s2c0 += v0 * v0;
            s1c1 += v1; s2c1 += v1 * v1;
        }
    }

    s1c0 += __shfl_xor(s1c0, 16); s1c0 += __shfl_xor(s1c0, 32);
    s2c0 += __shfl_xor(s2c0, 16); s2c0 += __shfl_xor(s2c0, 32);
    s1c1 += __shfl_xor(s1c1, 16); s1c1 += __shfl_xor(s1c1, 32);
    s2c1 += __shfl_xor(s2c1, 16); s2c1 += __shfl_xor(s2c1, 32);
    if (l < 16) wsum[w][l] = make_float4(s1c0, s2c0, s1c1, s2c1);
    __syncthreads();
    if (tid < 32) {
        int ch = tid >> 4, oo = tid & 15;
        float a = 0.f, b = 0.f;
#pragma unroll
        for (int ww = 0; ww < 4; ww++) {
            float4 v = wsum[ww][oo];
            a += ch ? v.z : v.x;
            b += ch ? v.w : v.y;
        }
        int s_idx = bs % NS, b_idx = bs / NS;
        int srow = s_idx * 16 + oo;
        int col  = b_idx * 32 + (c0 + ch);
        psum[srow * 256 + col] = a;
        psq [srow * 256 + col] = b;
    }
}

// ---------------------------------------------------------------------------
// Kernel 3: reduce BN partials -> scale/shift per (s,o). 384 WGs of 256.
// ---------------------------------------------------------------------------
__global__ __launch_bounds__(256) void k_bnstat(const float* __restrict__ psum,
                                                const float* __restrict__ psq,
                                                const float* __restrict__ gamma,
                                                const float* __restrict__ beta,
                                                float* __restrict__ scale,
                                                float* __restrict__ shift) {
    __shared__ float l1[4], l2[4];
    int row = blockIdx.x;
    int t = threadIdx.x;
    float s = psum[row * 256 + t], q = psq[row * 256 + t];
    for (int off = 32; off; off >>= 1) {
        s += __shfl_down(s, off);
        q += __shfl_down(q, off);
    }
    if ((t & 63) == 0) { l1[t >> 6] = s; l2[t >> 6] = q; }
    __syncthreads();
    if (t == 0) {
        s = l1[0] + l1[1] + l1[2] + l1[3];
        q = l2[0] + l2[1] + l2[2] + l2[3];
        float mean = s * (1.0f / BN_COUNT);
        float var  = q * (1.0f / BN_COUNT) - mean * mean;
        float inv  = rsqrtf(var + 1e-5f);
        int o = row & 15;
        float sc = gamma[o] * inv;
        scale[row] = sc;
        shift[row] = beta[o] - mean * sc;
    }
}

// ---------------------------------------------------------------------------
// Kernel 4: BN + relu + layer 3 + relu. WG per (bs, c2-PAIR): LDS packs
// {z_c0, z_c1} bf16x2 per node -> one gather serves 2 output points.
// ---------------------------------------------------------------------------
__global__ __launch_bounds__(256) void k_layer3(const __hip_bfloat16* __restrict__ y2,
                                                const int* __restrict__ G3Q,
                                                const float* __restrict__ scale,
                                                const float* __restrict__ shift,
                                                const float* __restrict__ W3,
                                                const float* __restrict__ b3,
                                                float* __restrict__ out) {
    __shared__ __align__(16) unsigned int zl[4096];
    int blk = blockIdx.x;                 // 1536 = 192 bs * 8 c2-pairs
    int cpp = blk & 7, bs = blk >> 3;
    int c0 = cpp * 2;
    int s = bs % NS;
    float sc0 = scale[s * 16 + c0],     sh0 = shift[s * 16 + c0];
    float sc1 = scale[s * 16 + c0 + 1], sh1 = shift[s * 16 + c0 + 1];
    const unsigned int* yb0 = (const unsigned int*)(y2 + ((size_t)bs * NC2 + c0) * NN);
    const unsigned int* yb1 = (const unsigned int*)(y2 + ((size_t)bs * NC2 + c0 + 1) * NN);
    uint2* zl2 = (uint2*)zl;
    for (int j = threadIdx.x; j < 2048; j += 256) {
        unsigned int u0 = yb0[j], u1 = yb1[j];
        float a0 = fmaxf(fmaf(__uint_as_float(u0 << 16),          sc0, sh0), 0.f);
        float a1 = fmaxf(fmaf(__uint_as_float(u0 & 0xffff0000u),  sc0, sh0), 0.f);
        float b0 = fmaxf(fmaf(__uint_as_float(u1 << 16),          sc1, sh1), 0.f);
        float b1 = fmaxf(fmaf(__uint_as_float(u1 & 0xffff0000u),  sc1, sh1), 0.f);
        __hip_bfloat16 ba0 = __float2bfloat16(a0), bb0 = __float2bfloat16(b0);
        __hip_bfloat16 ba1 = __float2bfloat16(a1), bb1 = __float2bfloat16(b1);
        uint2 p;
        p.x = (unsigned int)*(unsigned short*)&ba0 | ((unsigned int)*(unsigned short*)&bb0 << 16);
        p.y = (unsigned int)*(unsigned short*)&ba1 | ((unsigned int)*(unsigned short*)&bb1 << 16);
        zl2[j] = p;
    }
    __syncthreads();
    int r = threadIdx.x;
    const int4* gq = (const int4*)G3Q;
    float acc0 = b3[0], acc1 = b3[0];
    for (int m4 = 0; m4 < 36; m4 += 2) {
        int4 qa = gq[m4 * 256 + r];
        int4 qb = gq[(m4 + 1) * 256 + r];
        unsigned int dd[8] = {zl[qa.x], zl[qa.y], zl[qa.z], zl[qa.w],
                              zl[qb.x], zl[qb.y], zl[qb.z], zl[qb.w]};
#pragma unroll
        for (int jj = 0; jj < 8; jj++) {
            float wv = W3[m4 * 4 + jj];           // wave-uniform -> scalar
            acc0 = fmaf(__uint_as_float(dd[jj] << 16),         wv, acc0);
            acc1 = fmaf(__uint_as_float(dd[jj] & 0xffff0000u), wv, acc1);
        }
    }
    float* ob = out + (size_t)bs * NN + c0 * 256 + r;
    ob[0]   = fmaxf(acc0, 0.f);
    ob[256] = fmaxf(acc1, 0.f);
}

// ---------------------------------------------------------------------------
extern "C" void kernel_launch(void* const* d_in, const int* in_sizes, int n_in,
                              void* d_out, int out_size, void* d_ws, size_t ws_size,
                              hipStream_t stream) {
    const float* input = (const float*)d_in[0];
    const int*   neigh = (const int*)d_in[1];
    const float* W1    = (const float*)d_in[2];
    const float* b1    = (const float*)d_in[3];
    const float* W2    = (const float*)d_in[4];
    const float* b2    = (const float*)d_in[5];
    const float* gamma = (const float*)d_in[6];
    const float* beta  = (const float*)d_in[7];
    const float* W3    = (const float*)d_in[8];
    const float* b3    = (const float*)d_in[9];
    float* out = (float*)d_out;

    // Workspace layout (bytes), total ~76.6 MB (all offsets 16B-aligned)
    char* ws = (char*)d_ws;
    int*            G2M   = (int*)            (ws);             // 147456
    int*            G3Q   = (int*)            (ws + 147456);    // 147456
    __hip_bfloat16* W2B   = (__hip_bfloat16*) (ws + 294912);    // 9216
    __hip_bfloat16* h     = (__hip_bfloat16*) (ws + 304128);    // 50331648
    __hip_bfloat16* y2    = (__hip_bfloat16*) (ws + 50635776);  // 25165824
    float*          psum  = (float*)          (ws + 75801600);  // 393216
    float*          psq   = (float*)          (ws + 76194816);  // 393216
    float*          scale = (float*)          (ws + 76588032);  // 1536
    float*          shift = (float*)          (ws + 76589568);  // 1536

    k_tables<<<306, 256, 0, stream>>>(neigh, G2M, G3Q, W2, W2B);
    k_layer1<<<1536, 256, 0, stream>>>(input, W1, b1, h);
    k_layer2<<<3072, 256, 0, stream>>>(h, (const int4*)G2M, (const int4*)W2B,
                                       b2, y2, psum, psq);
    k_bnstat<<<384, 256, 0, stream>>>(psum, psq, gamma, beta, scale, shift);
    k_layer3<<<1536, 256, 0, stream>>>(y2, G3Q, scale, shift, W3, b3, out);
}

// Round 6
// 161.551 us; speedup vs baseline: 3.5734x; 1.0016x over previous
//
#include <hip/hip_runtime.h>
#include <hip/hip_bf16.h>

// Problem constants (B=8,S=24,N=4096,K=9,C1=32,C2=16)
#define NB 8
#define NS 24
#define NN 4096
#define NC1 32
#define NC2 16
#define BN_COUNT 32768.0f

typedef float f32x4 __attribute__((ext_vector_type(4)));
typedef short bf16x8 __attribute__((ext_vector_type(8)));
union U8 { int4 i; bf16x8 b; };
union Q  { uint4 v; unsigned u[4]; };

#define PERM_LO 0x05040100u
#define PERM_HI 0x07060302u
// __builtin_amdgcn_perm(a, b, sel): bytes 0-3 = b, 4-7 = a.
// PERM_LO -> {lo16(b), lo16(a)} ; PERM_HI -> {hi16(b), hi16(a)}

__device__ __forceinline__ unsigned short bfbits(float x) {
    __hip_bfloat16 h = __float2bfloat16(x);
    return *(unsigned short*)&h;
}

// ---------------------------------------------------------------------------
// Kernel 0: tables.
//  G2M[((t*9+kb)*64+l)*8+j], t<8:  r=t*16+(l&15), k=kb*32+(l>>4)*8+j,
//     rem=r*288+k, val=neigh[(rem&4095)*9+(rem>>12)]
//  G3M[((t*5+kb)*64+l)*8+j], t<16: r=t*16+(l&15), k=kb*32+(l>>4)*8+j,
//     k<144 ? neigh[((r*144+k)&4095)*9+((r*144+k)>>12)] : 0
//  W2B[kb*512+l*8+j] = bf16 W2[o=l&15][k]   (B-frag order)
//  W3B[kb*512+l*8+j] = bf16 (o==0 && k<144 ? W3[k] : 0)
// ---------------------------------------------------------------------------
__global__ void k_tables(const int* __restrict__ neigh,
                         int* __restrict__ G2M, int* __restrict__ G3M,
                         const float* __restrict__ W2, const float* __restrict__ W3,
                         __hip_bfloat16* __restrict__ W2B,
                         __hip_bfloat16* __restrict__ W3B) {
    int j = blockIdx.x * 256 + threadIdx.x;          // grid = 332*256 = 84992
    if (j < 36864) {                                 // G2M
        int j8 = j & 7;
        int tkbl = j >> 3;
        int l = tkbl & 63;
        int tkb = tkbl >> 6;                         // < 72
        int t = tkb / 9, kb = tkb - t * 9;
        int r = t * 16 + (l & 15);
        int k = kb * 32 + ((l >> 4) << 3) + j8;
        int rem = r * 288 + k;
        G2M[j] = neigh[(rem & 4095) * 9 + (rem >> 12)];
    } else if (j < 77824) {                          // G3M (40960)
        int t2 = j - 36864;
        int j8 = t2 & 7;
        int tkbl = t2 >> 3;
        int l = tkbl & 63;
        int tkb = tkbl >> 6;                         // < 80
        int t = tkb / 5, kb = tkb - t * 5;
        int r = t * 16 + (l & 15);
        int k = kb * 32 + ((l >> 4) << 3) + j8;
        int rem = r * 144 + k;
        G3M[t2] = (k < 144) ? neigh[(rem & 4095) * 9 + (rem >> 12)] : 0;
    } else if (j < 82432) {                          // W2B (4608)
        int jj = j - 77824;
        int kb = jj >> 9;
        int rest = jj & 511;
        int l = rest >> 3, j8 = rest & 7;
        int o = l & 15;
        int k = kb * 32 + ((l >> 4) << 3) + j8;
        W2B[jj] = __float2bfloat16(W2[o * 288 + k]);
    } else {                                         // W3B (2560)
        int jj = j - 82432;
        int kb = jj >> 9;
        int rest = jj & 511;
        int l = rest >> 3, j8 = rest & 7;
        int o = l & 15;
        int k = kb * 32 + ((l >> 4) << 3) + j8;
        W3B[jj] = __float2bfloat16((o == 0 && k < 144) ? W3[k] : 0.f);
    }
}

// ---------------------------------------------------------------------------
// Kernel 1: layer 1 -> h in 4 octet planes h[pl][bs][n][8ch] (16 B/node).
// Input-window tiling (R5, no over-fetch).
// ---------------------------------------------------------------------------
__global__ __launch_bounds__(256) void k_layer1(const float* __restrict__ input,
                                                const float* __restrict__ W1,
                                                const float* __restrict__ b1,
                                                uint4* __restrict__ hp) {
    __shared__ __align__(16) float win[4680];
    __shared__ __align__(16) float corner[72];
    int blk = blockIdx.x;                 // 1536 = 192 bs * 8 windows
    int w = blk & 7, bs = blk >> 3;
    int n0 = w * 512;
    const float* A = input + (size_t)bs * 36864;
    int base = n0 * 9;
    int cnt4 = min(4680, 36864 - base) >> 2;
    const float4* A4 = (const float4*)(A + base);
    float4* win4 = (float4*)win;
    for (int j = threadIdx.x; j < cnt4; j += 256) win4[j] = A4[j];
    if (threadIdx.x < 18) ((float4*)corner)[threadIdx.x] = ((const float4*)A)[threadIdx.x];
    __syncthreads();

    for (int i = threadIdx.x; i < 522; i += 256) {
        int j = i / 58, off = i - j * 58;
        int x = j * 4096 + n0;
        int pstart = (x + 8) / 9;
        int pend   = (x + 520) / 9;
        int p = pstart + off;
        if (p >= pend) continue;
        int nf = (p * 9) & 4095;
        float v[9];
        int wb = (nf - n0) * 9 + j;
        if (nf <= 4087) {
#pragma unroll
            for (int m = 0; m < 9; m++) v[m] = win[wb + 9 * m];
        } else {
            int nw = 4096 - nf;
#pragma unroll
            for (int m = 0; m < 9; m++)
                v[m] = (m < nw) ? win[wb + 9 * m]
                                : corner[(nf + m - 4096) * 9 + j + 1];
        }
        float acc[32];
#pragma unroll 4
        for (int c = 0; c < 32; c++) {
            float a = b1[c];
#pragma unroll
            for (int m = 0; m < 9; m++) a = fmaf(v[m], W1[c * 9 + m], a);
            acc[c] = fmaxf(a, 0.f);
        }
#pragma unroll
        for (int pl = 0; pl < 4; pl++) {
            uint4 d;
            d.x = (unsigned)bfbits(acc[pl * 8 + 0]) | ((unsigned)bfbits(acc[pl * 8 + 1]) << 16);
            d.y = (unsigned)bfbits(acc[pl * 8 + 2]) | ((unsigned)bfbits(acc[pl * 8 + 3]) << 16);
            d.z = (unsigned)bfbits(acc[pl * 8 + 4]) | ((unsigned)bfbits(acc[pl * 8 + 5]) << 16);
            d.w = (unsigned)bfbits(acc[pl * 8 + 6]) | ((unsigned)bfbits(acc[pl * 8 + 7]) << 16);
            hp[((size_t)pl * 192 + bs) * NN + p] = d;
        }
    }
}

// ---------------------------------------------------------------------------
// Kernel 2: layer 2 via MFMA with 8-channel-shared b128 gathers.
// WG per (bs, pl, rhalf): stage 64KB octet plane; per wave one 16-r tile;
// per kb: 8 ds_read_b128 (8ch x 8 nodes) -> 32 v_perm transpose -> 8 MFMAs.
// y2 written as 2 octet planes [o>>3][bs][n][8o]. Deterministic BN partials.
// ---------------------------------------------------------------------------
__global__ __launch_bounds__(256) void k_layer2(const uint4* __restrict__ hp,
                                                const int4* __restrict__ G2M4,
                                                const int4* __restrict__ W2B4,
                                                const float* __restrict__ b2,
                                                __hip_bfloat16* __restrict__ y2p,
                                                float* __restrict__ psum,
                                                float* __restrict__ psq) {
    __shared__ __align__(16) uint4 hl[4096];
    __shared__ float wred[2][4][16];
    int blk = blockIdx.x;                 // 1536 = 192 bs * 4 pl * 2 rh
    int rh = blk & 1, pl = (blk >> 1) & 3, bs = blk >> 3;
    const uint4* hb = hp + ((size_t)pl * 192 + bs) * NN;
    for (int j = threadIdx.x; j < 4096; j += 256) hl[j] = hb[j];
    __syncthreads();

    int tid = threadIdx.x;
    int l = tid & 63, w = tid >> 6;
    int o = l & 15, q = l >> 4;
    int t = rh * 4 + w;                   // r-tile 0..7

    U8 bfrag[9];
#pragma unroll
    for (int kb = 0; kb < 9; kb++) bfrag[kb].i = W2B4[kb * 64 + l];
    float bb = b2[o];

    f32x4 acc[8];
#pragma unroll
    for (int c = 0; c < 8; c++) acc[c] = (f32x4){0.f, 0.f, 0.f, 0.f};

    const int4* gp = G2M4 + (size_t)(t * 9) * 128 + l * 2;
#pragma unroll
    for (int kb = 0; kb < 9; kb++) {
        int4 ia = gp[kb * 128];
        int4 ib = gp[kb * 128 + 1];
        Q d[8];
        d[0].v = hl[ia.x]; d[1].v = hl[ia.y]; d[2].v = hl[ia.z]; d[3].v = hl[ia.w];
        d[4].v = hl[ib.x]; d[5].v = hl[ib.y]; d[6].v = hl[ib.z]; d[7].v = hl[ib.w];
#pragma unroll
        for (int c = 0; c < 8; c++) {
            const int q2 = c >> 1;
            const unsigned sel = (c & 1) ? PERM_HI : PERM_LO;
            U8 Af;
            Af.i.x = __builtin_amdgcn_perm(d[1].u[q2], d[0].u[q2], sel);
            Af.i.y = __builtin_amdgcn_perm(d[3].u[q2], d[2].u[q2], sel);
            Af.i.z = __builtin_amdgcn_perm(d[5].u[q2], d[4].u[q2], sel);
            Af.i.w = __builtin_amdgcn_perm(d[7].u[q2], d[6].u[q2], sel);
            acc[c] = __builtin_amdgcn_mfma_f32_16x16x32_bf16(Af.b, bfrag[kb].b, acc[c], 0, 0, 0);
        }
    }

    // epilogue: bias, y2 octet-plane store, BN partials
    float s1 = 0.f, s2 = 0.f;
    int rbase = t * 16 + q * 4;
    __hip_bfloat16* ypl = y2p + (((size_t)(o >> 3) * 192 + bs) * NN) * 8 + (o & 7);
#pragma unroll
    for (int c = 0; c < 8; c++) {
        int C = pl * 8 + c;               // layer-2 input channel -> n-block
#pragma unroll
        for (int i = 0; i < 4; i++) {
            float v = acc[c][i] + bb;
            s1 += v; s2 += v * v;
            int n = C * 128 + rbase + i;
            ypl[(size_t)n * 8] = __float2bfloat16(v);
        }
    }
    s1 += __shfl_xor(s1, 16); s1 += __shfl_xor(s1, 32);
    s2 += __shfl_xor(s2, 16); s2 += __shfl_xor(s2, 32);
    if (l < 16) { wred[0][w][l] = s1; wred[1][w][l] = s2; }
    __syncthreads();
    if (tid < 16) {
        float a = wred[0][0][tid] + wred[0][1][tid] + wred[0][2][tid] + wred[0][3][tid];
        float b = wred[1][0][tid] + wred[1][1][tid] + wred[1][2][tid] + wred[1][3][tid];
        int srow = (bs % NS) * 16 + tid;
        int col  = (bs / NS) * 8 + pl * 2 + rh;   // 64 cols
        psum[srow * 64 + col] = a;
        psq [srow * 64 + col] = b;
    }
}

// ---------------------------------------------------------------------------
// Kernel 3: reduce 64 BN partials -> scale/shift per (s,o). 384 x 64.
// ---------------------------------------------------------------------------
__global__ __launch_bounds__(64) void k_bnstat(const float* __restrict__ psum,
                                               const float* __restrict__ psq,
                                               const float* __restrict__ gamma,
                                               const float* __restrict__ beta,
                                               float* __restrict__ scale,
                                               float* __restrict__ shift) {
    int row = blockIdx.x;
    int t = threadIdx.x;
    float s = psum[row * 64 + t], q = psq[row * 64 + t];
    for (int off = 32; off; off >>= 1) {
        s += __shfl_down(s, off);
        q += __shfl_down(q, off);
    }
    if (t == 0) {
        float mean = s * (1.0f / BN_COUNT);
        float var  = q * (1.0f / BN_COUNT) - mean * mean;
        float inv  = rsqrtf(var + 1e-5f);
        int o = row & 15;
        float sc = gamma[o] * inv;
        scale[row] = sc;
        shift[row] = beta[o] - mean * sc;
    }
}

// ---------------------------------------------------------------------------
// Kernel 4: BN + relu + layer 3 (via MFMA, B = [W3|0..0]) + relu.
// WG per (bs, pl(2), rhalf): stage BN'd octet plane (64KB); per wave two
// 16-r tiles; per kb: 8 b128 gathers -> 32 perms -> 8 MFMAs (col 0 used).
// ---------------------------------------------------------------------------
__global__ __launch_bounds__(256) void k_layer3(const uint4* __restrict__ y2p,
                                                const int4* __restrict__ G3M4,
                                                const int4* __restrict__ W3B4,
                                                const float* __restrict__ scale,
                                                const float* __restrict__ shift,
                                                const float* __restrict__ b3,
                                                float* __restrict__ out) {
    __shared__ __align__(16) uint4 zl[4096];
    int blk = blockIdx.x;                 // 768 = 192 bs * 2 pl * 2 rh
    int rh = blk & 1, pl = (blk >> 1) & 1, bs = blk >> 2;
    int s = bs % NS;
    float sc[8], sh[8];
#pragma unroll
    for (int jj = 0; jj < 8; jj++) {
        sc[jj] = scale[s * 16 + pl * 8 + jj];
        sh[jj] = shift[s * 16 + pl * 8 + jj];
    }
    const uint4* yb = y2p + ((size_t)pl * 192 + bs) * NN;
    for (int j = threadIdx.x; j < 4096; j += 256) {
        uint4 u = yb[j];
        unsigned r[4] = {u.x, u.y, u.z, u.w};
        uint4 pk;
        unsigned* pp = (unsigned*)&pk;
#pragma unroll
        for (int dd = 0; dd < 4; dd++) {
            float lo = fmaxf(fmaf(__uint_as_float(r[dd] << 16),         sc[dd*2],   sh[dd*2]),   0.f);
            float hi = fmaxf(fmaf(__uint_as_float(r[dd] & 0xffff0000u), sc[dd*2+1], sh[dd*2+1]), 0.f);
            unsigned ulo = __float_as_uint(lo) + 0x8000u;   // round-half-up to bf16
            unsigned uhi = __float_as_uint(hi) + 0x8000u;
            pp[dd] = __builtin_amdgcn_perm(uhi, ulo, PERM_HI);
        }
        zl[j] = pk;
    }
    __syncthreads();

    int tid = threadIdx.x;
    int l = tid & 63, w = tid >> 6;
    int o = l & 15, q = l >> 4;
    float b3v = b3[0];

    U8 bfrag[5];
#pragma unroll
    for (int kb = 0; kb < 5; kb++) bfrag[kb].i = W3B4[kb * 64 + l];

#pragma unroll
    for (int tt = 0; tt < 2; tt++) {
        int t = rh * 8 + w * 2 + tt;      // r-tile 0..15
        f32x4 acc[8];
#pragma unroll
        for (int c = 0; c < 8; c++) acc[c] = (f32x4){0.f, 0.f, 0.f, 0.f};
        const int4* gp = G3M4 + (size_t)(t * 5) * 128 + l * 2;
#pragma unroll
        for (int kb = 0; kb < 5; kb++) {
            int4 ia = gp[kb * 128];
            int4 ib = gp[kb * 128 + 1];
            Q d[8];
            d[0].v = zl[ia.x]; d[1].v = zl[ia.y]; d[2].v = zl[ia.z]; d[3].v = zl[ia.w];
            d[4].v = zl[ib.x]; d[5].v = zl[ib.y]; d[6].v = zl[ib.z]; d[7].v = zl[ib.w];
#pragma unroll
            for (int c = 0; c < 8; c++) {
                const int q2 = c >> 1;
                const unsigned sel = (c & 1) ? PERM_HI : PERM_LO;
                U8 Af;
                Af.i.x = __builtin_amdgcn_perm(d[1].u[q2], d[0].u[q2], sel);
                Af.i.y = __builtin_amdgcn_perm(d[3].u[q2], d[2].u[q2], sel);
                Af.i.z = __builtin_amdgcn_perm(d[5].u[q2], d[4].u[q2], sel);
                Af.i.w = __builtin_amdgcn_perm(d[7].u[q2], d[6].u[q2], sel);
                acc[c] = __builtin_amdgcn_mfma_f32_16x16x32_bf16(Af.b, bfrag[kb].b, acc[c], 0, 0, 0);
            }
        }
        if (o == 0) {                     // C col 0 holds the result
            int rbase = t * 16 + q * 4;
            float* ob = out + (size_t)bs * NN + pl * 8 * 256 + rbase;
#pragma unroll
            for (int c = 0; c < 8; c++)
#pragma unroll
                for (int i = 0; i < 4; i++)
                    ob[c * 256 + i] = fmaxf(acc[c][i] + b3v, 0.f);
        }
    }
}

// ---------------------------------------------------------------------------
extern "C" void kernel_launch(void* const* d_in, const int* in_sizes, int n_in,
                              void* d_out, int out_size, void* d_ws, size_t ws_size,
                              hipStream_t stream) {
    const float* input = (const float*)d_in[0];
    const int*   neigh = (const int*)d_in[1];
    const float* W1    = (const float*)d_in[2];
    const float* b1    = (const float*)d_in[3];
    const float* W2    = (const float*)d_in[4];
    const float* b2    = (const float*)d_in[5];
    const float* gamma = (const float*)d_in[6];
    const float* beta  = (const float*)d_in[7];
    const float* W3    = (const float*)d_in[8];
    const float* b3    = (const float*)d_in[9];
    float* out = (float*)d_out;

    // Workspace layout (bytes), total ~76.0 MB, all 16B-aligned
    char* ws = (char*)d_ws;
    int*            G2M   = (int*)            (ws);             // 147456
    int*            G3M   = (int*)            (ws + 147456);    // 163840
    __hip_bfloat16* W2B   = (__hip_bfloat16*) (ws + 311296);    // 9216
    __hip_bfloat16* W3B   = (__hip_bfloat16*) (ws + 320512);    // 5120
    uint4*          h     = (uint4*)          (ws + 325632);    // 50331648
    __hip_bfloat16* y2    = (__hip_bfloat16*) (ws + 50657280);  // 25165824
    float*          psum  = (float*)          (ws + 75823104);  // 98304
    float*          psq   = (float*)          (ws + 75921408);  // 98304
    float*          scale = (float*)          (ws + 76019712);  // 1536
    float*          shift = (float*)          (ws + 76021248);  // 1536

    k_tables<<<332, 256, 0, stream>>>(neigh, G2M, G3M, W2, W3, W2B, W3B);
    k_layer1<<<1536, 256, 0, stream>>>(input, W1, b1, h);
    k_layer2<<<1536, 256, 0, stream>>>(h, (const int4*)G2M, (const int4*)W2B,
                                       b2, y2, psum, psq);
    k_bnstat<<<384, 64, 0, stream>>>(psum, psq, gamma, beta, scale, shift);
    k_layer3<<<768, 256, 0, stream>>>((const uint4*)y2, (const int4*)G3M,
                                      (const int4*)W3B, scale, shift, b3, out);
}

// Round 8
// 148.507 us; speedup vs baseline: 3.8873x; 1.0878x over previous
//
#include <hip/hip_runtime.h>
#include <hip/hip_bf16.h>

// Problem constants (B=8,S=24,N=4096,K=9,C1=32,C2=16)
#define NB 8
#define NS 24
#define NN 4096
#define NC1 32
#define NC2 16
#define BN_COUNT 32768.0f

typedef float f32x4 __attribute__((ext_vector_type(4)));
typedef short bf16x8 __attribute__((ext_vector_type(8)));
union U8 { int4 i; bf16x8 b; };
union Q  { uint4 v; unsigned u[4]; };

#define PERM_LO 0x05040100u
#define PERM_HI 0x07060302u
// __builtin_amdgcn_perm(a, b, sel): bytes 0-3 = b, 4-7 = a.
// PERM_LO -> {lo16(b), lo16(a)} ; PERM_HI -> {hi16(b), hi16(a)}

__device__ __forceinline__ unsigned short bfbits(float x) {
    __hip_bfloat16 h = __float2bfloat16(x);
    return *(unsigned short*)&h;
}

// ---------------------------------------------------------------------------
// Kernel 0: tables (unchanged, proven R6).
// ---------------------------------------------------------------------------
__global__ void k_tables(const int* __restrict__ neigh,
                         int* __restrict__ G2M, int* __restrict__ G3M,
                         const float* __restrict__ W2, const float* __restrict__ W3,
                         __hip_bfloat16* __restrict__ W2B,
                         __hip_bfloat16* __restrict__ W3B) {
    int j = blockIdx.x * 256 + threadIdx.x;          // grid = 332*256 = 84992
    if (j < 36864) {                                 // G2M
        int j8 = j & 7;
        int tkbl = j >> 3;
        int l = tkbl & 63;
        int tkb = tkbl >> 6;                         // < 72
        int t = tkb / 9, kb = tkb - t * 9;
        int r = t * 16 + (l & 15);
        int k = kb * 32 + ((l >> 4) << 3) + j8;
        int rem = r * 288 + k;
        G2M[j] = neigh[(rem & 4095) * 9 + (rem >> 12)];
    } else if (j < 77824) {                          // G3M (40960)
        int t2 = j - 36864;
        int j8 = t2 & 7;
        int tkbl = t2 >> 3;
        int l = tkbl & 63;
        int tkb = tkbl >> 6;                         // < 80
        int t = tkb / 5, kb = tkb - t * 5;
        int r = t * 16 + (l & 15);
        int k = kb * 32 + ((l >> 4) << 3) + j8;
        int rem = r * 144 + k;
        G3M[t2] = (k < 144) ? neigh[(rem & 4095) * 9 + (rem >> 12)] : 0;
    } else if (j < 82432) {                          // W2B (4608)
        int jj = j - 77824;
        int kb = jj >> 9;
        int rest = jj & 511;
        int l = rest >> 3, j8 = rest & 7;
        int o = l & 15;
        int k = kb * 32 + ((l >> 4) << 3) + j8;
        W2B[jj] = __float2bfloat16(W2[o * 288 + k]);
    } else {                                         // W3B (2560)
        int jj = j - 82432;
        int kb = jj >> 9;
        int rest = jj & 511;
        int l = rest >> 3, j8 = rest & 7;
        int o = l & 15;
        int k = kb * 32 + ((l >> 4) << 3) + j8;
        W3B[jj] = __float2bfloat16((o == 0 && k < 144) ? W3[k] : 0.f);
    }
}

// ---------------------------------------------------------------------------
// Kernel 1: layer 1 -> h in 4 octet planes h[pl][bs][n][8ch] (16 B/node).
// Input-window tiling (no over-fetch). Unchanged, proven R6.
// ---------------------------------------------------------------------------
__global__ __launch_bounds__(256) void k_layer1(const float* __restrict__ input,
                                                const float* __restrict__ W1,
                                                const float* __restrict__ b1,
                                                uint4* __restrict__ hp) {
    __shared__ __align__(16) float win[4680];
    __shared__ __align__(16) float corner[72];
    int blk = blockIdx.x;                 // 1536 = 192 bs * 8 windows
    int w = blk & 7, bs = blk >> 3;
    int n0 = w * 512;
    const float* A = input + (size_t)bs * 36864;
    int base = n0 * 9;
    int cnt4 = min(4680, 36864 - base) >> 2;
    const float4* A4 = (const float4*)(A + base);
    float4* win4 = (float4*)win;
    for (int j = threadIdx.x; j < cnt4; j += 256) win4[j] = A4[j];
    if (threadIdx.x < 18) ((float4*)corner)[threadIdx.x] = ((const float4*)A)[threadIdx.x];
    __syncthreads();

    for (int i = threadIdx.x; i < 522; i += 256) {
        int j = i / 58, off = i - j * 58;
        int x = j * 4096 + n0;
        int pstart = (x + 8) / 9;
        int pend   = (x + 520) / 9;
        int p = pstart + off;
        if (p >= pend) continue;
        int nf = (p * 9) & 4095;
        float v[9];
        int wb = (nf - n0) * 9 + j;
        if (nf <= 4087) {
#pragma unroll
            for (int m = 0; m < 9; m++) v[m] = win[wb + 9 * m];
        } else {
            int nw = 4096 - nf;
#pragma unroll
            for (int m = 0; m < 9; m++)
                v[m] = (m < nw) ? win[wb + 9 * m]
                                : corner[(nf + m - 4096) * 9 + j + 1];
        }
        float acc[32];
#pragma unroll 4
        for (int c = 0; c < 32; c++) {
            float a = b1[c];
#pragma unroll
            for (int m = 0; m < 9; m++) a = fmaf(v[m], W1[c * 9 + m], a);
            acc[c] = fmaxf(a, 0.f);
        }
#pragma unroll
        for (int pl = 0; pl < 4; pl++) {
            uint4 d;
            d.x = (unsigned)bfbits(acc[pl * 8 + 0]) | ((unsigned)bfbits(acc[pl * 8 + 1]) << 16);
            d.y = (unsigned)bfbits(acc[pl * 8 + 2]) | ((unsigned)bfbits(acc[pl * 8 + 3]) << 16);
            d.z = (unsigned)bfbits(acc[pl * 8 + 4]) | ((unsigned)bfbits(acc[pl * 8 + 5]) << 16);
            d.w = (unsigned)bfbits(acc[pl * 8 + 6]) | ((unsigned)bfbits(acc[pl * 8 + 7]) << 16);
            hp[((size_t)pl * 192 + bs) * NN + p] = d;
        }
    }
}

// ---------------------------------------------------------------------------
// Kernel 2: layer 2 via MFMA. 256-thread WG per (bs, pl): stage the 64KB
// octet plane ONCE; 4 waves x 2 r-tiles (tt loop). K-loop and scattered-bf16
// epilogue are the R6-proven code verbatim.
// ---------------------------------------------------------------------------
__global__ __launch_bounds__(256) void k_layer2(const uint4* __restrict__ hp,
                                                const int4* __restrict__ G2M4,
                                                const int4* __restrict__ W2B4,
                                                const float* __restrict__ b2,
                                                __hip_bfloat16* __restrict__ y2p,
                                                float* __restrict__ psum,
                                                float* __restrict__ psq) {
    __shared__ __align__(16) uint4 hl[4096];       // 64 KB
    __shared__ float wred[2][4][16];
    int blk = blockIdx.x;                 // 768 = 192 bs * 4 pl
    int pl = blk & 3, bs = blk >> 2;
    const uint4* hb = hp + ((size_t)pl * 192 + bs) * NN;
    for (int j = threadIdx.x; j < 4096; j += 256) hl[j] = hb[j];
    __syncthreads();

    int tid = threadIdx.x;
    int l = tid & 63, w = tid >> 6;       // w = 0..3
    int o = l & 15, q = l >> 4;
    float bb = b2[o];

    U8 bfrag[9];
#pragma unroll
    for (int kb = 0; kb < 9; kb++) bfrag[kb].i = W2B4[kb * 64 + l];

    float s1 = 0.f, s2 = 0.f;
    __hip_bfloat16* ypl = y2p + (((size_t)(o >> 3) * 192 + bs) * NN) * 8 + (o & 7);

#pragma unroll
    for (int tt = 0; tt < 2; tt++) {
        int t = tt * 4 + w;               // r-tile 0..7
        f32x4 acc[8];
#pragma unroll
        for (int c = 0; c < 8; c++) acc[c] = (f32x4){0.f, 0.f, 0.f, 0.f};

        const int4* gp = G2M4 + (size_t)(t * 9) * 128 + l * 2;
#pragma unroll
        for (int kb = 0; kb < 9; kb++) {
            int4 ia = gp[kb * 128];
            int4 ib = gp[kb * 128 + 1];
            Q d[8];
            d[0].v = hl[ia.x]; d[1].v = hl[ia.y]; d[2].v = hl[ia.z]; d[3].v = hl[ia.w];
            d[4].v = hl[ib.x]; d[5].v = hl[ib.y]; d[6].v = hl[ib.z]; d[7].v = hl[ib.w];
#pragma unroll
            for (int c = 0; c < 8; c++) {
                const int q2 = c >> 1;
                const unsigned sel = (c & 1) ? PERM_HI : PERM_LO;
                U8 Af;
                Af.i.x = __builtin_amdgcn_perm(d[1].u[q2], d[0].u[q2], sel);
                Af.i.y = __builtin_amdgcn_perm(d[3].u[q2], d[2].u[q2], sel);
                Af.i.z = __builtin_amdgcn_perm(d[5].u[q2], d[4].u[q2], sel);
                Af.i.w = __builtin_amdgcn_perm(d[7].u[q2], d[6].u[q2], sel);
                acc[c] = __builtin_amdgcn_mfma_f32_16x16x32_bf16(Af.b, bfrag[kb].b, acc[c], 0, 0, 0);
            }
        }

        // R6-proven epilogue: scattered bf16 stores into y2 octet planes
        int rbase = t * 16 + q * 4;
#pragma unroll
        for (int c = 0; c < 8; c++) {
            int C = pl * 8 + c;           // layer-2 input channel -> n-block
#pragma unroll
            for (int i = 0; i < 4; i++) {
                float v = acc[c][i] + bb;
                s1 += v; s2 += v * v;
                int n = C * 128 + rbase + i;
                ypl[(size_t)n * 8] = __float2bfloat16(v);
            }
        }
    }

    s1 += __shfl_xor(s1, 16); s1 += __shfl_xor(s1, 32);
    s2 += __shfl_xor(s2, 16); s2 += __shfl_xor(s2, 32);
    if (l < 16) { wred[0][w][l] = s1; wred[1][w][l] = s2; }
    __syncthreads();
    if (tid < 16) {
        float a = wred[0][0][tid] + wred[0][1][tid] + wred[0][2][tid] + wred[0][3][tid];
        float b = wred[1][0][tid] + wred[1][1][tid] + wred[1][2][tid] + wred[1][3][tid];
        int srow = (bs % NS) * 16 + tid;
        int col  = (bs / NS) * 4 + pl;    // 32 cols
        psum[srow * 32 + col] = a;
        psq [srow * 32 + col] = b;
    }
}

// ---------------------------------------------------------------------------
// Kernel 3: reduce 32 BN partials -> scale/shift per (s,o). 384 x 64.
// ---------------------------------------------------------------------------
__global__ __launch_bounds__(64) void k_bnstat(const float* __restrict__ psum,
                                               const float* __restrict__ psq,
                                               const float* __restrict__ gamma,
                                               const float* __restrict__ beta,
                                               float* __restrict__ scale,
                                               float* __restrict__ shift) {
    int row = blockIdx.x;
    int t = threadIdx.x;
    float s = (t < 32) ? psum[row * 32 + t] : 0.f;
    float q = (t < 32) ? psq [row * 32 + t] : 0.f;
    for (int off = 16; off; off >>= 1) {
        s += __shfl_down(s, off);
        q += __shfl_down(q, off);
    }
    if (t == 0) {
        float mean = s * (1.0f / BN_COUNT);
        float var  = q * (1.0f / BN_COUNT) - mean * mean;
        float inv  = rsqrtf(var + 1e-5f);
        int o = row & 15;
        float sc = gamma[o] * inv;
        scale[row] = sc;
        shift[row] = beta[o] - mean * sc;
    }
}

// ---------------------------------------------------------------------------
// Kernel 4: BN + relu + layer 3 (MFMA, B=[W3|0..]) + relu. 256-thread WG
// per (bs, oct): stage BN'd plane ONCE; 4 waves x 4 r-tiles (tt loop).
// Staging, K-loop, and o==0 direct store are the R6-proven code verbatim.
// ---------------------------------------------------------------------------
__global__ __launch_bounds__(256) void k_layer3(const uint4* __restrict__ y2p,
                                                const int4* __restrict__ G3M4,
                                                const int4* __restrict__ W3B4,
                                                const float* __restrict__ scale,
                                                const float* __restrict__ shift,
                                                const float* __restrict__ b3,
                                                float* __restrict__ out) {
    __shared__ __align__(16) uint4 zl[4096];       // 64 KB
    int blk = blockIdx.x;                 // 384 = 192 bs * 2 oct
    int oct = blk & 1, bs = blk >> 1;
    int s = bs % NS;
    float sc[8], sh[8];
#pragma unroll
    for (int jj = 0; jj < 8; jj++) {
        sc[jj] = scale[s * 16 + oct * 8 + jj];
        sh[jj] = shift[s * 16 + oct * 8 + jj];
    }
    const uint4* yb = y2p + ((size_t)oct * 192 + bs) * NN;
    for (int j = threadIdx.x; j < 4096; j += 256) {
        uint4 u = yb[j];
        unsigned r[4] = {u.x, u.y, u.z, u.w};
        uint4 pk;
        unsigned* pp = (unsigned*)&pk;
#pragma unroll
        for (int dd = 0; dd < 4; dd++) {
            float lo = fmaxf(fmaf(__uint_as_float(r[dd] << 16),         sc[dd*2],   sh[dd*2]),   0.f);
            float hi = fmaxf(fmaf(__uint_as_float(r[dd] & 0xffff0000u), sc[dd*2+1], sh[dd*2+1]), 0.f);
            unsigned ulo = __float_as_uint(lo) + 0x8000u;   // round to bf16
            unsigned uhi = __float_as_uint(hi) + 0x8000u;
            pp[dd] = __builtin_amdgcn_perm(uhi, ulo, PERM_HI);
        }
        zl[j] = pk;
    }
    __syncthreads();

    int tid = threadIdx.x;
    int l = tid & 63, w = tid >> 6;       // w = 0..3
    int o = l & 15, q = l >> 4;
    float b3v = b3[0];

    U8 bfrag[5];
#pragma unroll
    for (int kb = 0; kb < 5; kb++) bfrag[kb].i = W3B4[kb * 64 + l];

#pragma unroll
    for (int tt = 0; tt < 4; tt++) {
        int t = tt * 4 + w;               // r-tile 0..15
        f32x4 acc[8];
#pragma unroll
        for (int c = 0; c < 8; c++) acc[c] = (f32x4){0.f, 0.f, 0.f, 0.f};
        const int4* gp = G3M4 + (size_t)(t * 5) * 128 + l * 2;
#pragma unroll
        for (int kb = 0; kb < 5; kb++) {
            int4 ia = gp[kb * 128];
            int4 ib = gp[kb * 128 + 1];
            Q d[8];
            d[0].v = zl[ia.x]; d[1].v = zl[ia.y]; d[2].v = zl[ia.z]; d[3].v = zl[ia.w];
            d[4].v = zl[ib.x]; d[5].v = zl[ib.y]; d[6].v = zl[ib.z]; d[7].v = zl[ib.w];
#pragma unroll
            for (int c = 0; c < 8; c++) {
                const int q2 = c >> 1;
                const unsigned sel = (c & 1) ? PERM_HI : PERM_LO;
                U8 Af;
                Af.i.x = __builtin_amdgcn_perm(d[1].u[q2], d[0].u[q2], sel);
                Af.i.y = __builtin_amdgcn_perm(d[3].u[q2], d[2].u[q2], sel);
                Af.i.z = __builtin_amdgcn_perm(d[5].u[q2], d[4].u[q2], sel);
                Af.i.w = __builtin_amdgcn_perm(d[7].u[q2], d[6].u[q2], sel);
                acc[c] = __builtin_amdgcn_mfma_f32_16x16x32_bf16(Af.b, bfrag[kb].b, acc[c], 0, 0, 0);
            }
        }
        if (o == 0) {                     // C col 0 holds the result
            int rbase = t * 16 + q * 4;
            float* ob = out + (size_t)bs * NN + oct * 2048;
#pragma unroll
            for (int c = 0; c < 8; c++)
#pragma unroll
                for (int i = 0; i < 4; i++)
                    ob[c * 256 + rbase + i] = fmaxf(acc[c][i] + b3v, 0.f);
        }
    }
}

// ---------------------------------------------------------------------------
extern "C" void kernel_launch(void* const* d_in, const int* in_sizes, int n_in,
                              void* d_out, int out_size, void* d_ws, size_t ws_size,
                              hipStream_t stream) {
    const float* input = (const float*)d_in[0];
    const int*   neigh = (const int*)d_in[1];
    const float* W1    = (const float*)d_in[2];
    const float* b1    = (const float*)d_in[3];
    const float* W2    = (const float*)d_in[4];
    const float* b2    = (const float*)d_in[5];
    const float* gamma = (const float*)d_in[6];
    const float* beta  = (const float*)d_in[7];
    const float* W3    = (const float*)d_in[8];
    const float* b3    = (const float*)d_in[9];
    float* out = (float*)d_out;

    // Workspace layout (bytes), all 16B-aligned
    char* ws = (char*)d_ws;
    int*            G2M   = (int*)            (ws);             // 147456
    int*            G3M   = (int*)            (ws + 147456);    // 163840
    __hip_bfloat16* W2B   = (__hip_bfloat16*) (ws + 311296);    // 9216
    __hip_bfloat16* W3B   = (__hip_bfloat16*) (ws + 320512);    // 5120
    uint4*          h     = (uint4*)          (ws + 325632);    // 50331648
    __hip_bfloat16* y2    = (__hip_bfloat16*) (ws + 50657280);  // 25165824
    float*          psum  = (float*)          (ws + 75823104);  // 49152
    float*          psq   = (float*)          (ws + 75872256);  // 49152
    float*          scale = (float*)          (ws + 75921408);  // 1536
    float*          shift = (float*)          (ws + 75922944);  // 1536

    k_tables<<<332, 256, 0, stream>>>(neigh, G2M, G3M, W2, W3, W2B, W3B);
    k_layer1<<<1536, 256, 0, stream>>>(input, W1, b1, h);
    k_layer2<<<768, 256, 0, stream>>>(h, (const int4*)G2M, (const int4*)W2B,
                                      b2, y2, psum, psq);
    k_bnstat<<<384, 64, 0, stream>>>(psum, psq, gamma, beta, scale, shift);
    k_layer3<<<384, 256, 0, stream>>>((const uint4*)y2, (const int4*)G3M,
                                      (const int4*)W3B, scale, shift, b3, out);
}

// Round 9
// 144.970 us; speedup vs baseline: 3.9821x; 1.0244x over previous
//
#include <hip/hip_runtime.h>
#include <hip/hip_bf16.h>

// Problem constants (B=8,S=24,N=4096,K=9,C1=32,C2=16)
#define NB 8
#define NS 24
#define NN 4096
#define NC1 32
#define NC2 16
#define BN_COUNT 32768.0f

typedef float f32x4 __attribute__((ext_vector_type(4)));
typedef short bf16x8 __attribute__((ext_vector_type(8)));
union U8 { int4 i; bf16x8 b; };
union Q  { uint4 v; unsigned u[4]; };

#define PERM_LO 0x05040100u
#define PERM_HI 0x07060302u
// __builtin_amdgcn_perm(a, b, sel): bytes 0-3 = b, 4-7 = a.
// PERM_LO -> {lo16(b), lo16(a)} ; PERM_HI -> {hi16(b), hi16(a)}

__device__ __forceinline__ unsigned short bfbits(float x) {
    __hip_bfloat16 h = __float2bfloat16(x);
    return *(unsigned short*)&h;
}

// ---------------------------------------------------------------------------
// Kernel 1: layer 1 (R8-proven body) + fused table builder.
// Blocks [0,1536): layer-1 input-window tiling -> h octet planes.
// Blocks [1536,1868): build G2M/G3M/W2B/W3B (consumed by later kernels only;
// kernel boundary guarantees visibility).
// ---------------------------------------------------------------------------
__global__ __launch_bounds__(256) void k_l1tab(const float* __restrict__ input,
                                               const float* __restrict__ W1,
                                               const float* __restrict__ b1,
                                               uint4* __restrict__ hp,
                                               const int* __restrict__ neigh,
                                               int* __restrict__ G2M,
                                               int* __restrict__ G3M,
                                               const float* __restrict__ W2,
                                               const float* __restrict__ W3,
                                               __hip_bfloat16* __restrict__ W2B,
                                               __hip_bfloat16* __restrict__ W3B) {
    __shared__ __align__(16) float win[4680];
    __shared__ __align__(16) float corner[72];
    int blk = blockIdx.x;                 // 1868 = 1536 l1 + 332 tables
    if (blk >= 1536) {
        int j = (blk - 1536) * 256 + threadIdx.x;    // < 84992
        if (j < 36864) {                             // G2M
            int j8 = j & 7;
            int tkbl = j >> 3;
            int l = tkbl & 63;
            int tkb = tkbl >> 6;                     // < 72
            int t = tkb / 9, kb = tkb - t * 9;
            int r = t * 16 + (l & 15);
            int k = kb * 32 + ((l >> 4) << 3) + j8;
            int rem = r * 288 + k;
            G2M[j] = neigh[(rem & 4095) * 9 + (rem >> 12)];
        } else if (j < 77824) {                      // G3M (40960)
            int t2 = j - 36864;
            int j8 = t2 & 7;
            int tkbl = t2 >> 3;
            int l = tkbl & 63;
            int tkb = tkbl >> 6;                     // < 80
            int t = tkb / 5, kb = tkb - t * 5;
            int r = t * 16 + (l & 15);
            int k = kb * 32 + ((l >> 4) << 3) + j8;
            int rem = r * 144 + k;
            G3M[t2] = (k < 144) ? neigh[(rem & 4095) * 9 + (rem >> 12)] : 0;
        } else if (j < 82432) {                      // W2B (4608)
            int jj = j - 77824;
            int kb = jj >> 9;
            int rest = jj & 511;
            int l = rest >> 3, j8 = rest & 7;
            int o = l & 15;
            int k = kb * 32 + ((l >> 4) << 3) + j8;
            W2B[jj] = __float2bfloat16(W2[o * 288 + k]);
        } else {                                     // W3B (2560)
            int jj = j - 82432;
            int kb = jj >> 9;
            int rest = jj & 511;
            int l = rest >> 3, j8 = rest & 7;
            int o = l & 15;
            int k = kb * 32 + ((l >> 4) << 3) + j8;
            W3B[jj] = __float2bfloat16((o == 0 && k < 144) ? W3[k] : 0.f);
        }
        return;
    }

    int w = blk & 7, bs = blk >> 3;
    int n0 = w * 512;
    const float* A = input + (size_t)bs * 36864;
    int base = n0 * 9;
    int cnt4 = min(4680, 36864 - base) >> 2;
    const float4* A4 = (const float4*)(A + base);
    float4* win4 = (float4*)win;
    for (int j = threadIdx.x; j < cnt4; j += 256) win4[j] = A4[j];
    if (threadIdx.x < 18) ((float4*)corner)[threadIdx.x] = ((const float4*)A)[threadIdx.x];
    __syncthreads();

    for (int i = threadIdx.x; i < 522; i += 256) {
        int j = i / 58, off = i - j * 58;
        int x = j * 4096 + n0;
        int pstart = (x + 8) / 9;
        int pend   = (x + 520) / 9;
        int p = pstart + off;
        if (p >= pend) continue;
        int nf = (p * 9) & 4095;
        float v[9];
        int wb = (nf - n0) * 9 + j;
        if (nf <= 4087) {
#pragma unroll
            for (int m = 0; m < 9; m++) v[m] = win[wb + 9 * m];
        } else {
            int nw = 4096 - nf;
#pragma unroll
            for (int m = 0; m < 9; m++)
                v[m] = (m < nw) ? win[wb + 9 * m]
                                : corner[(nf + m - 4096) * 9 + j + 1];
        }
        float acc[32];
#pragma unroll 4
        for (int c = 0; c < 32; c++) {
            float a = b1[c];
#pragma unroll
            for (int m = 0; m < 9; m++) a = fmaf(v[m], W1[c * 9 + m], a);
            acc[c] = fmaxf(a, 0.f);
        }
#pragma unroll
        for (int pl = 0; pl < 4; pl++) {
            uint4 d;
            d.x = (unsigned)bfbits(acc[pl * 8 + 0]) | ((unsigned)bfbits(acc[pl * 8 + 1]) << 16);
            d.y = (unsigned)bfbits(acc[pl * 8 + 2]) | ((unsigned)bfbits(acc[pl * 8 + 3]) << 16);
            d.z = (unsigned)bfbits(acc[pl * 8 + 4]) | ((unsigned)bfbits(acc[pl * 8 + 5]) << 16);
            d.w = (unsigned)bfbits(acc[pl * 8 + 6]) | ((unsigned)bfbits(acc[pl * 8 + 7]) << 16);
            hp[((size_t)pl * 192 + bs) * NN + p] = d;
        }
    }
}

// ---------------------------------------------------------------------------
// Kernel 2: layer 2 via MFMA (R8-proven, unchanged). 256-thread WG per
// (bs, pl): stage the 64KB octet plane ONCE; 4 waves x 2 r-tiles.
// ---------------------------------------------------------------------------
__global__ __launch_bounds__(256) void k_layer2(const uint4* __restrict__ hp,
                                                const int4* __restrict__ G2M4,
                                                const int4* __restrict__ W2B4,
                                                const float* __restrict__ b2,
                                                __hip_bfloat16* __restrict__ y2p,
                                                float* __restrict__ psum,
                                                float* __restrict__ psq) {
    __shared__ __align__(16) uint4 hl[4096];       // 64 KB
    __shared__ float wred[2][4][16];
    int blk = blockIdx.x;                 // 768 = 192 bs * 4 pl
    int pl = blk & 3, bs = blk >> 2;
    const uint4* hb = hp + ((size_t)pl * 192 + bs) * NN;
    for (int j = threadIdx.x; j < 4096; j += 256) hl[j] = hb[j];
    __syncthreads();

    int tid = threadIdx.x;
    int l = tid & 63, w = tid >> 6;       // w = 0..3
    int o = l & 15, q = l >> 4;
    float bb = b2[o];

    U8 bfrag[9];
#pragma unroll
    for (int kb = 0; kb < 9; kb++) bfrag[kb].i = W2B4[kb * 64 + l];

    float s1 = 0.f, s2 = 0.f;
    __hip_bfloat16* ypl = y2p + (((size_t)(o >> 3) * 192 + bs) * NN) * 8 + (o & 7);

#pragma unroll
    for (int tt = 0; tt < 2; tt++) {
        int t = tt * 4 + w;               // r-tile 0..7
        f32x4 acc[8];
#pragma unroll
        for (int c = 0; c < 8; c++) acc[c] = (f32x4){0.f, 0.f, 0.f, 0.f};

        const int4* gp = G2M4 + (size_t)(t * 9) * 128 + l * 2;
#pragma unroll
        for (int kb = 0; kb < 9; kb++) {
            int4 ia = gp[kb * 128];
            int4 ib = gp[kb * 128 + 1];
            Q d[8];
            d[0].v = hl[ia.x]; d[1].v = hl[ia.y]; d[2].v = hl[ia.z]; d[3].v = hl[ia.w];
            d[4].v = hl[ib.x]; d[5].v = hl[ib.y]; d[6].v = hl[ib.z]; d[7].v = hl[ib.w];
#pragma unroll
            for (int c = 0; c < 8; c++) {
                const int q2 = c >> 1;
                const unsigned sel = (c & 1) ? PERM_HI : PERM_LO;
                U8 Af;
                Af.i.x = __builtin_amdgcn_perm(d[1].u[q2], d[0].u[q2], sel);
                Af.i.y = __builtin_amdgcn_perm(d[3].u[q2], d[2].u[q2], sel);
                Af.i.z = __builtin_amdgcn_perm(d[5].u[q2], d[4].u[q2], sel);
                Af.i.w = __builtin_amdgcn_perm(d[7].u[q2], d[6].u[q2], sel);
                acc[c] = __builtin_amdgcn_mfma_f32_16x16x32_bf16(Af.b, bfrag[kb].b, acc[c], 0, 0, 0);
            }
        }

        // scattered bf16 stores into y2 octet planes
        int rbase = t * 16 + q * 4;
#pragma unroll
        for (int c = 0; c < 8; c++) {
            int C = pl * 8 + c;           // layer-2 input channel -> n-block
#pragma unroll
            for (int i = 0; i < 4; i++) {
                float v = acc[c][i] + bb;
                s1 += v; s2 += v * v;
                int n = C * 128 + rbase + i;
                ypl[(size_t)n * 8] = __float2bfloat16(v);
            }
        }
    }

    s1 += __shfl_xor(s1, 16); s1 += __shfl_xor(s1, 32);
    s2 += __shfl_xor(s2, 16); s2 += __shfl_xor(s2, 32);
    if (l < 16) { wred[0][w][l] = s1; wred[1][w][l] = s2; }
    __syncthreads();
    if (tid < 16) {
        float a = wred[0][0][tid] + wred[0][1][tid] + wred[0][2][tid] + wred[0][3][tid];
        float b = wred[1][0][tid] + wred[1][1][tid] + wred[1][2][tid] + wred[1][3][tid];
        int srow = (bs % NS) * 16 + tid;
        int col  = (bs / NS) * 4 + pl;    // 32 cols
        psum[srow * 32 + col] = a;
        psq [srow * 32 + col] = b;
    }
}

// ---------------------------------------------------------------------------
// Kernel 3: fused BN-stat reduce + BN + relu + layer 3 (MFMA) + relu.
// Prologue: each WG deterministically reduces its own 8 (s,o) rows of the
// 32-column partials (width-32 shuffle) -> scl/shf in LDS. Then the
// R8-proven staging / K-loop / o==0 store.
// ---------------------------------------------------------------------------
__global__ __launch_bounds__(256) void k_l3bn(const uint4* __restrict__ y2p,
                                              const int4* __restrict__ G3M4,
                                              const int4* __restrict__ W3B4,
                                              const float* __restrict__ psum,
                                              const float* __restrict__ psq,
                                              const float* __restrict__ gamma,
                                              const float* __restrict__ beta,
                                              const float* __restrict__ b3,
                                              float* __restrict__ out) {
    __shared__ __align__(16) uint4 zl[4096];       // 64 KB
    __shared__ float scl[8], shf[8];
    int blk = blockIdx.x;                 // 384 = 192 bs * 2 oct
    int oct = blk & 1, bs = blk >> 1;
    int s = bs % NS;
    int tid = threadIdx.x;

    {   // BN stat reduce: 8 rows x 32 cols, one value per thread
        int jj = tid >> 5, col = tid & 31;
        int row = s * 16 + oct * 8 + jj;
        float sv = psum[row * 32 + col];
        float qv = psq [row * 32 + col];
        for (int off = 16; off; off >>= 1) {
            sv += __shfl_down(sv, off, 32);
            qv += __shfl_down(qv, off, 32);
        }
        if (col == 0) {
            float mean = sv * (1.0f / BN_COUNT);
            float var  = qv * (1.0f / BN_COUNT) - mean * mean;
            float inv  = rsqrtf(var + 1e-5f);
            int o = oct * 8 + jj;
            float scv = gamma[o] * inv;
            scl[jj] = scv;
            shf[jj] = beta[o] - mean * scv;
        }
    }
    __syncthreads();

    float sc[8], sh[8];
#pragma unroll
    for (int jj = 0; jj < 8; jj++) { sc[jj] = scl[jj]; sh[jj] = shf[jj]; }

    const uint4* yb = y2p + ((size_t)oct * 192 + bs) * NN;
    for (int j = tid; j < 4096; j += 256) {
        uint4 u = yb[j];
        unsigned r[4] = {u.x, u.y, u.z, u.w};
        uint4 pk;
        unsigned* pp = (unsigned*)&pk;
#pragma unroll
        for (int dd = 0; dd < 4; dd++) {
            float lo = fmaxf(fmaf(__uint_as_float(r[dd] << 16),         sc[dd*2],   sh[dd*2]),   0.f);
            float hi = fmaxf(fmaf(__uint_as_float(r[dd] & 0xffff0000u), sc[dd*2+1], sh[dd*2+1]), 0.f);
            unsigned ulo = __float_as_uint(lo) + 0x8000u;   // round to bf16
            unsigned uhi = __float_as_uint(hi) + 0x8000u;
            pp[dd] = __builtin_amdgcn_perm(uhi, ulo, PERM_HI);
        }
        zl[j] = pk;
    }
    __syncthreads();

    int l = tid & 63, w = tid >> 6;       // w = 0..3
    int o = l & 15, q = l >> 4;
    float b3v = b3[0];

    U8 bfrag[5];
#pragma unroll
    for (int kb = 0; kb < 5; kb++) bfrag[kb].i = W3B4[kb * 64 + l];

#pragma unroll
    for (int tt = 0; tt < 4; tt++) {
        int t = tt * 4 + w;               // r-tile 0..15
        f32x4 acc[8];
#pragma unroll
        for (int c = 0; c < 8; c++) acc[c] = (f32x4){0.f, 0.f, 0.f, 0.f};
        const int4* gp = G3M4 + (size_t)(t * 5) * 128 + l * 2;
#pragma unroll
        for (int kb = 0; kb < 5; kb++) {
            int4 ia = gp[kb * 128];
            int4 ib = gp[kb * 128 + 1];
            Q d[8];
            d[0].v = zl[ia.x]; d[1].v = zl[ia.y]; d[2].v = zl[ia.z]; d[3].v = zl[ia.w];
            d[4].v = zl[ib.x]; d[5].v = zl[ib.y]; d[6].v = zl[ib.z]; d[7].v = zl[ib.w];
#pragma unroll
            for (int c = 0; c < 8; c++) {
                const int q2 = c >> 1;
                const unsigned sel = (c & 1) ? PERM_HI : PERM_LO;
                U8 Af;
                Af.i.x = __builtin_amdgcn_perm(d[1].u[q2], d[0].u[q2], sel);
                Af.i.y = __builtin_amdgcn_perm(d[3].u[q2], d[2].u[q2], sel);
                Af.i.z = __builtin_amdgcn_perm(d[5].u[q2], d[4].u[q2], sel);
                Af.i.w = __builtin_amdgcn_perm(d[7].u[q2], d[6].u[q2], sel);
                acc[c] = __builtin_amdgcn_mfma_f32_16x16x32_bf16(Af.b, bfrag[kb].b, acc[c], 0, 0, 0);
            }
        }
        if (o == 0) {                     // C col 0 holds the result
            int rbase = t * 16 + q * 4;
            float* ob = out + (size_t)bs * NN + oct * 2048;
#pragma unroll
            for (int c = 0; c < 8; c++)
#pragma unroll
                for (int i = 0; i < 4; i++)
                    ob[c * 256 + rbase + i] = fmaxf(acc[c][i] + b3v, 0.f);
        }
    }
}

// ---------------------------------------------------------------------------
extern "C" void kernel_launch(void* const* d_in, const int* in_sizes, int n_in,
                              void* d_out, int out_size, void* d_ws, size_t ws_size,
                              hipStream_t stream) {
    const float* input = (const float*)d_in[0];
    const int*   neigh = (const int*)d_in[1];
    const float* W1    = (const float*)d_in[2];
    const float* b1    = (const float*)d_in[3];
    const float* W2    = (const float*)d_in[4];
    const float* b2    = (const float*)d_in[5];
    const float* gamma = (const float*)d_in[6];
    const float* beta  = (const float*)d_in[7];
    const float* W3    = (const float*)d_in[8];
    const float* b3    = (const float*)d_in[9];
    float* out = (float*)d_out;

    // Workspace layout (bytes), all 16B-aligned
    char* ws = (char*)d_ws;
    int*            G2M   = (int*)            (ws);             // 147456
    int*            G3M   = (int*)            (ws + 147456);    // 163840
    __hip_bfloat16* W2B   = (__hip_bfloat16*) (ws + 311296);    // 9216
    __hip_bfloat16* W3B   = (__hip_bfloat16*) (ws + 320512);    // 5120
    uint4*          h     = (uint4*)          (ws + 325632);    // 50331648
    __hip_bfloat16* y2    = (__hip_bfloat16*) (ws + 50657280);  // 25165824
    float*          psum  = (float*)          (ws + 75823104);  // 49152
    float*          psq   = (float*)          (ws + 75872256);  // 49152

    k_l1tab<<<1868, 256, 0, stream>>>(input, W1, b1, h,
                                      neigh, G2M, G3M, W2, W3, W2B, W3B);
    k_layer2<<<768, 256, 0, stream>>>(h, (const int4*)G2M, (const int4*)W2B,
                                      b2, y2, psum, psq);
    k_l3bn<<<384, 256, 0, stream>>>((const uint4*)y2, (const int4*)G3M,
                                    (const int4*)W3B, psum, psq,
                                    gamma, beta, b3, out);
}

// Round 10
// 138.984 us; speedup vs baseline: 4.1536x; 1.0431x over previous
//
#include <hip/hip_runtime.h>
#include <hip/hip_bf16.h>

// Problem constants (B=8,S=24,N=4096,K=9,C1=32,C2=16)
#define NB 8
#define NS 24
#define NN 4096
#define NC1 32
#define NC2 16
#define BN_COUNT 32768.0f

typedef float f32x4 __attribute__((ext_vector_type(4)));
typedef short bf16x8 __attribute__((ext_vector_type(8)));
union U8 { int4 i; bf16x8 b; };
union Q  { uint4 v; unsigned u[4]; };

#define PERM_LO 0x05040100u
#define PERM_HI 0x07060302u
// __builtin_amdgcn_perm(a, b, sel): bytes 0-3 = b, 4-7 = a.
// PERM_LO -> {lo16(b), lo16(a)} ; PERM_HI -> {hi16(b), hi16(a)}

__device__ __forceinline__ unsigned short bfbits(float x) {
    __hip_bfloat16 h = __float2bfloat16(x);
    return *(unsigned short*)&h;
}

// ---------------------------------------------------------------------------
// Kernel 1: layer 1 (proven body) + fused table builder (proven R9).
// ---------------------------------------------------------------------------
__global__ __launch_bounds__(256) void k_l1tab(const float* __restrict__ input,
                                               const float* __restrict__ W1,
                                               const float* __restrict__ b1,
                                               uint4* __restrict__ hp,
                                               const int* __restrict__ neigh,
                                               int* __restrict__ G2M,
                                               int* __restrict__ G3M,
                                               const float* __restrict__ W2,
                                               const float* __restrict__ W3,
                                               __hip_bfloat16* __restrict__ W2B,
                                               __hip_bfloat16* __restrict__ W3B) {
    __shared__ __align__(16) float win[4680];
    __shared__ __align__(16) float corner[72];
    int blk = blockIdx.x;                 // 1868 = 1536 l1 + 332 tables
    if (blk >= 1536) {
        int j = (blk - 1536) * 256 + threadIdx.x;    // < 84992
        if (j < 36864) {                             // G2M
            int j8 = j & 7;
            int tkbl = j >> 3;
            int l = tkbl & 63;
            int tkb = tkbl >> 6;                     // < 72
            int t = tkb / 9, kb = tkb - t * 9;
            int r = t * 16 + (l & 15);
            int k = kb * 32 + ((l >> 4) << 3) + j8;
            int rem = r * 288 + k;
            G2M[j] = neigh[(rem & 4095) * 9 + (rem >> 12)];
        } else if (j < 77824) {                      // G3M (40960)
            int t2 = j - 36864;
            int j8 = t2 & 7;
            int tkbl = t2 >> 3;
            int l = tkbl & 63;
            int tkb = tkbl >> 6;                     // < 80
            int t = tkb / 5, kb = tkb - t * 5;
            int r = t * 16 + (l & 15);
            int k = kb * 32 + ((l >> 4) << 3) + j8;
            int rem = r * 144 + k;
            G3M[t2] = (k < 144) ? neigh[(rem & 4095) * 9 + (rem >> 12)] : 0;
        } else if (j < 82432) {                      // W2B (4608)
            int jj = j - 77824;
            int kb = jj >> 9;
            int rest = jj & 511;
            int l = rest >> 3, j8 = rest & 7;
            int o = l & 15;
            int k = kb * 32 + ((l >> 4) << 3) + j8;
            W2B[jj] = __float2bfloat16(W2[o * 288 + k]);
        } else {                                     // W3B (2560)
            int jj = j - 82432;
            int kb = jj >> 9;
            int rest = jj & 511;
            int l = rest >> 3, j8 = rest & 7;
            int o = l & 15;
            int k = kb * 32 + ((l >> 4) << 3) + j8;
            W3B[jj] = __float2bfloat16((o == 0 && k < 144) ? W3[k] : 0.f);
        }
        return;
    }

    int w = blk & 7, bs = blk >> 3;
    int n0 = w * 512;
    const float* A = input + (size_t)bs * 36864;
    int base = n0 * 9;
    int cnt4 = min(4680, 36864 - base) >> 2;
    const float4* A4 = (const float4*)(A + base);
    float4* win4 = (float4*)win;
    for (int j = threadIdx.x; j < cnt4; j += 256) win4[j] = A4[j];
    if (threadIdx.x < 18) ((float4*)corner)[threadIdx.x] = ((const float4*)A)[threadIdx.x];
    __syncthreads();

    for (int i = threadIdx.x; i < 522; i += 256) {
        int j = i / 58, off = i - j * 58;
        int x = j * 4096 + n0;
        int pstart = (x + 8) / 9;
        int pend   = (x + 520) / 9;
        int p = pstart + off;
        if (p >= pend) continue;
        int nf = (p * 9) & 4095;
        float v[9];
        int wb = (nf - n0) * 9 + j;
        if (nf <= 4087) {
#pragma unroll
            for (int m = 0; m < 9; m++) v[m] = win[wb + 9 * m];
        } else {
            int nw = 4096 - nf;
#pragma unroll
            for (int m = 0; m < 9; m++)
                v[m] = (m < nw) ? win[wb + 9 * m]
                                : corner[(nf + m - 4096) * 9 + j + 1];
        }
        float acc[32];
#pragma unroll 4
        for (int c = 0; c < 32; c++) {
            float a = b1[c];
#pragma unroll
            for (int m = 0; m < 9; m++) a = fmaf(v[m], W1[c * 9 + m], a);
            acc[c] = fmaxf(a, 0.f);
        }
#pragma unroll
        for (int pl = 0; pl < 4; pl++) {
            uint4 d;
            d.x = (unsigned)bfbits(acc[pl * 8 + 0]) | ((unsigned)bfbits(acc[pl * 8 + 1]) << 16);
            d.y = (unsigned)bfbits(acc[pl * 8 + 2]) | ((unsigned)bfbits(acc[pl * 8 + 3]) << 16);
            d.z = (unsigned)bfbits(acc[pl * 8 + 4]) | ((unsigned)bfbits(acc[pl * 8 + 5]) << 16);
            d.w = (unsigned)bfbits(acc[pl * 8 + 6]) | ((unsigned)bfbits(acc[pl * 8 + 7]) << 16);
            hp[((size_t)pl * 192 + bs) * NN + p] = d;
        }
    }
}

// ---------------------------------------------------------------------------
// Kernel 2: layer 2 via MFMA. 512-thread WG per (bs, pl): 8 waves x 1 r-tile
// -> 16 waves/CU for latency hiding. K-loop + scattered epilogue are the
// R8/R9-proven code (B-frags streamed in-loop to stay under 128 VGPRs).
// ---------------------------------------------------------------------------
__global__ __launch_bounds__(512, 4) void k_layer2(const uint4* __restrict__ hp,
                                                   const int4* __restrict__ G2M4,
                                                   const int4* __restrict__ W2B4,
                                                   const float* __restrict__ b2,
                                                   __hip_bfloat16* __restrict__ y2p,
                                                   float* __restrict__ psum,
                                                   float* __restrict__ psq) {
    __shared__ __align__(16) uint4 hl[4096];       // 64 KB
    __shared__ float wred[2][8][16];
    int blk = blockIdx.x;                 // 768 = 192 bs * 4 pl
    int pl = blk & 3, bs = blk >> 2;
    const uint4* hb = hp + ((size_t)pl * 192 + bs) * NN;
    for (int j = threadIdx.x; j < 4096; j += 512) hl[j] = hb[j];
    __syncthreads();

    int tid = threadIdx.x;
    int l = tid & 63, w = tid >> 6;       // w = r-tile 0..7
    int o = l & 15, q = l >> 4;
    float bb = b2[o];

    float s1 = 0.f, s2 = 0.f;
    __hip_bfloat16* ypl = y2p + (((size_t)(o >> 3) * 192 + bs) * NN) * 8 + (o & 7);

    int t = w;                            // one r-tile per wave
    f32x4 acc[8];
#pragma unroll
    for (int c = 0; c < 8; c++) acc[c] = (f32x4){0.f, 0.f, 0.f, 0.f};

    const int4* gp = G2M4 + (size_t)(t * 9) * 128 + l * 2;
#pragma unroll
    for (int kb = 0; kb < 9; kb++) {
        U8 bf;
        bf.i = W2B4[kb * 64 + l];         // streamed, L2-hot
        int4 ia = gp[kb * 128];
        int4 ib = gp[kb * 128 + 1];
        Q d[8];
        d[0].v = hl[ia.x]; d[1].v = hl[ia.y]; d[2].v = hl[ia.z]; d[3].v = hl[ia.w];
        d[4].v = hl[ib.x]; d[5].v = hl[ib.y]; d[6].v = hl[ib.z]; d[7].v = hl[ib.w];
#pragma unroll
        for (int c = 0; c < 8; c++) {
            const int q2 = c >> 1;
            const unsigned sel = (c & 1) ? PERM_HI : PERM_LO;
            U8 Af;
            Af.i.x = __builtin_amdgcn_perm(d[1].u[q2], d[0].u[q2], sel);
            Af.i.y = __builtin_amdgcn_perm(d[3].u[q2], d[2].u[q2], sel);
            Af.i.z = __builtin_amdgcn_perm(d[5].u[q2], d[4].u[q2], sel);
            Af.i.w = __builtin_amdgcn_perm(d[7].u[q2], d[6].u[q2], sel);
            acc[c] = __builtin_amdgcn_mfma_f32_16x16x32_bf16(Af.b, bf.b, acc[c], 0, 0, 0);
        }
    }

    // proven epilogue: scattered bf16 stores into y2 octet planes
    int rbase = t * 16 + q * 4;
#pragma unroll
    for (int c = 0; c < 8; c++) {
        int C = pl * 8 + c;               // layer-2 input channel -> n-block
#pragma unroll
        for (int i = 0; i < 4; i++) {
            float v = acc[c][i] + bb;
            s1 += v; s2 += v * v;
            int n = C * 128 + rbase + i;
            ypl[(size_t)n * 8] = __float2bfloat16(v);
        }
    }

    s1 += __shfl_xor(s1, 16); s1 += __shfl_xor(s1, 32);
    s2 += __shfl_xor(s2, 16); s2 += __shfl_xor(s2, 32);
    if (l < 16) { wred[0][w][l] = s1; wred[1][w][l] = s2; }
    __syncthreads();
    if (tid < 16) {
        float a = 0.f, b = 0.f;
#pragma unroll
        for (int ww = 0; ww < 8; ww++) { a += wred[0][ww][tid]; b += wred[1][ww][tid]; }
        int srow = (bs % NS) * 16 + tid;
        int col  = (bs / NS) * 4 + pl;    // 32 cols
        psum[srow * 32 + col] = a;
        psq [srow * 32 + col] = b;
    }
}

// ---------------------------------------------------------------------------
// Kernel 3: fused BN-stat reduce + BN + relu + layer 3 (MFMA) + relu.
// 512-thread WG per (bs, oct): 8 waves x 2 r-tiles. Prologue guarded to
// tid<256; staging / K-loop / o==0 store are the R9-proven code.
// ---------------------------------------------------------------------------
__global__ __launch_bounds__(512, 4) void k_l3bn(const uint4* __restrict__ y2p,
                                                 const int4* __restrict__ G3M4,
                                                 const int4* __restrict__ W3B4,
                                                 const float* __restrict__ psum,
                                                 const float* __restrict__ psq,
                                                 const float* __restrict__ gamma,
                                                 const float* __restrict__ beta,
                                                 const float* __restrict__ b3,
                                                 float* __restrict__ out) {
    __shared__ __align__(16) uint4 zl[4096];       // 64 KB
    __shared__ float scl[8], shf[8];
    int blk = blockIdx.x;                 // 384 = 192 bs * 2 oct
    int oct = blk & 1, bs = blk >> 1;
    int s = bs % NS;
    int tid = threadIdx.x;

    if (tid < 256) {   // BN stat reduce: 8 rows x 32 cols, one value/thread
        int jj = tid >> 5, col = tid & 31;
        int row = s * 16 + oct * 8 + jj;
        float sv = psum[row * 32 + col];
        float qv = psq [row * 32 + col];
        for (int off = 16; off; off >>= 1) {
            sv += __shfl_down(sv, off, 32);
            qv += __shfl_down(qv, off, 32);
        }
        if (col == 0) {
            float mean = sv * (1.0f / BN_COUNT);
            float var  = qv * (1.0f / BN_COUNT) - mean * mean;
            float inv  = rsqrtf(var + 1e-5f);
            int o = oct * 8 + jj;
            float scv = gamma[o] * inv;
            scl[jj] = scv;
            shf[jj] = beta[o] - mean * scv;
        }
    }
    __syncthreads();

    float sc[8], sh[8];
#pragma unroll
    for (int jj = 0; jj < 8; jj++) { sc[jj] = scl[jj]; sh[jj] = shf[jj]; }

    const uint4* yb = y2p + ((size_t)oct * 192 + bs) * NN;
    for (int j = tid; j < 4096; j += 512) {
        uint4 u = yb[j];
        unsigned r[4] = {u.x, u.y, u.z, u.w};
        uint4 pk;
        unsigned* pp = (unsigned*)&pk;
#pragma unroll
        for (int dd = 0; dd < 4; dd++) {
            float lo = fmaxf(fmaf(__uint_as_float(r[dd] << 16),         sc[dd*2],   sh[dd*2]),   0.f);
            float hi = fmaxf(fmaf(__uint_as_float(r[dd] & 0xffff0000u), sc[dd*2+1], sh[dd*2+1]), 0.f);
            unsigned ulo = __float_as_uint(lo) + 0x8000u;   // round to bf16
            unsigned uhi = __float_as_uint(hi) + 0x8000u;
            pp[dd] = __builtin_amdgcn_perm(uhi, ulo, PERM_HI);
        }
        zl[j] = pk;
    }
    __syncthreads();

    int l = tid & 63, w = tid >> 6;       // w = 0..7
    int o = l & 15, q = l >> 4;
    float b3v = b3[0];

#pragma unroll
    for (int tt = 0; tt < 2; tt++) {
        int t = tt * 8 + w;               // r-tile 0..15
        f32x4 acc[8];
#pragma unroll
        for (int c = 0; c < 8; c++) acc[c] = (f32x4){0.f, 0.f, 0.f, 0.f};
        const int4* gp = G3M4 + (size_t)(t * 5) * 128 + l * 2;
#pragma unroll
        for (int kb = 0; kb < 5; kb++) {
            U8 bf;
            bf.i = W3B4[kb * 64 + l];
            int4 ia = gp[kb * 128];
            int4 ib = gp[kb * 128 + 1];
            Q d[8];
            d[0].v = zl[ia.x]; d[1].v = zl[ia.y]; d[2].v = zl[ia.z]; d[3].v = zl[ia.w];
            d[4].v = zl[ib.x]; d[5].v = zl[ib.y]; d[6].v = zl[ib.z]; d[7].v = zl[ib.w];
#pragma unroll
            for (int c = 0; c < 8; c++) {
                const int q2 = c >> 1;
                const unsigned sel = (c & 1) ? PERM_HI : PERM_LO;
                U8 Af;
                Af.i.x = __builtin_amdgcn_perm(d[1].u[q2], d[0].u[q2], sel);
                Af.i.y = __builtin_amdgcn_perm(d[3].u[q2], d[2].u[q2], sel);
                Af.i.z = __builtin_amdgcn_perm(d[5].u[q2], d[4].u[q2], sel);
                Af.i.w = __builtin_amdgcn_perm(d[7].u[q2], d[6].u[q2], sel);
                acc[c] = __builtin_amdgcn_mfma_f32_16x16x32_bf16(Af.b, bf.b, acc[c], 0, 0, 0);
            }
        }
        if (o == 0) {                     // C col 0 holds the result
            int rbase = t * 16 + q * 4;
            float* ob = out + (size_t)bs * NN + oct * 2048;
#pragma unroll
            for (int c = 0; c < 8; c++)
#pragma unroll
                for (int i = 0; i < 4; i++)
                    ob[c * 256 + rbase + i] = fmaxf(acc[c][i] + b3v, 0.f);
        }
    }
}

// ---------------------------------------------------------------------------
extern "C" void kernel_launch(void* const* d_in, const int* in_sizes, int n_in,
                              void* d_out, int out_size, void* d_ws, size_t ws_size,
                              hipStream_t stream) {
    const float* input = (const float*)d_in[0];
    const int*   neigh = (const int*)d_in[1];
    const float* W1    = (const float*)d_in[2];
    const float* b1    = (const float*)d_in[3];
    const float* W2    = (const float*)d_in[4];
    const float* b2    = (const float*)d_in[5];
    const float* gamma = (const float*)d_in[6];
    const float* beta  = (const float*)d_in[7];
    const float* W3    = (const float*)d_in[8];
    const float* b3    = (const float*)d_in[9];
    float* out = (float*)d_out;

    // Workspace layout (bytes), all 16B-aligned
    char* ws = (char*)d_ws;
    int*            G2M   = (int*)            (ws);             // 147456
    int*            G3M   = (int*)            (ws + 147456);    // 163840
    __hip_bfloat16* W2B   = (__hip_bfloat16*) (ws + 311296);    // 9216
    __hip_bfloat16* W3B   = (__hip_bfloat16*) (ws + 320512);    // 5120
    uint4*          h     = (uint4*)          (ws + 325632);    // 50331648
    __hip_bfloat16* y2    = (__hip_bfloat16*) (ws + 50657280);  // 25165824
    float*          psum  = (float*)          (ws + 75823104);  // 49152
    float*          psq   = (float*)          (ws + 75872256);  // 49152

    k_l1tab<<<1868, 256, 0, stream>>>(input, W1, b1, h,
                                      neigh, G2M, G3M, W2, W3, W2B, W3B);
    k_layer2<<<768, 512, 0, stream>>>(h, (const int4*)G2M, (const int4*)W2B,
                                      b2, y2, psum, psq);
    k_l3bn<<<384, 512, 0, stream>>>((const uint4*)y2, (const int4*)G3M,
                                    (const int4*)W3B, psum, psq,
                                    gamma, beta, b3, out);
}

// Round 11
// 138.255 us; speedup vs baseline: 4.1756x; 1.0053x over previous
//
#include <hip/hip_runtime.h>
#include <hip/hip_bf16.h>

// Problem constants (B=8,S=24,N=4096,K=9,C1=32,C2=16)
#define NB 8
#define NS 24
#define NN 4096
#define NC1 32
#define NC2 16
#define BN_COUNT 32768.0f

typedef float f32x4 __attribute__((ext_vector_type(4)));
typedef short bf16x8 __attribute__((ext_vector_type(8)));
union U8 { int4 i; bf16x8 b; };
union Q  { uint4 v; unsigned u[4]; };

#define PERM_LO 0x05040100u
#define PERM_HI 0x07060302u
// __builtin_amdgcn_perm(a, b, sel): bytes 0-3 = b, 4-7 = a.
// PERM_LO -> {lo16(b), lo16(a)} ; PERM_HI -> {hi16(b), hi16(a)}

__device__ __forceinline__ unsigned short bfbits(float x) {
    __hip_bfloat16 h = __float2bfloat16(x);
    return *(unsigned short*)&h;
}

// ---------------------------------------------------------------------------
// Kernel 1: layer 1 (proven body) + fused table builder (proven R9).
// ---------------------------------------------------------------------------
__global__ __launch_bounds__(256) void k_l1tab(const float* __restrict__ input,
                                               const float* __restrict__ W1,
                                               const float* __restrict__ b1,
                                               uint4* __restrict__ hp,
                                               const int* __restrict__ neigh,
                                               int* __restrict__ G2M,
                                               int* __restrict__ G3M,
                                               const float* __restrict__ W2,
                                               const float* __restrict__ W3,
                                               __hip_bfloat16* __restrict__ W2B,
                                               __hip_bfloat16* __restrict__ W3B) {
    __shared__ __align__(16) float win[4680];
    __shared__ __align__(16) float corner[72];
    int blk = blockIdx.x;                 // 1868 = 1536 l1 + 332 tables
    if (blk >= 1536) {
        int j = (blk - 1536) * 256 + threadIdx.x;    // < 84992
        if (j < 36864) {                             // G2M
            int j8 = j & 7;
            int tkbl = j >> 3;
            int l = tkbl & 63;
            int tkb = tkbl >> 6;                     // < 72
            int t = tkb / 9, kb = tkb - t * 9;
            int r = t * 16 + (l & 15);
            int k = kb * 32 + ((l >> 4) << 3) + j8;
            int rem = r * 288 + k;
            G2M[j] = neigh[(rem & 4095) * 9 + (rem >> 12)];
        } else if (j < 77824) {                      // G3M (40960)
            int t2 = j - 36864;
            int j8 = t2 & 7;
            int tkbl = t2 >> 3;
            int l = tkbl & 63;
            int tkb = tkbl >> 6;                     // < 80
            int t = tkb / 5, kb = tkb - t * 5;
            int r = t * 16 + (l & 15);
            int k = kb * 32 + ((l >> 4) << 3) + j8;
            int rem = r * 144 + k;
            G3M[t2] = (k < 144) ? neigh[(rem & 4095) * 9 + (rem >> 12)] : 0;
        } else if (j < 82432) {                      // W2B (4608)
            int jj = j - 77824;
            int kb = jj >> 9;
            int rest = jj & 511;
            int l = rest >> 3, j8 = rest & 7;
            int o = l & 15;
            int k = kb * 32 + ((l >> 4) << 3) + j8;
            W2B[jj] = __float2bfloat16(W2[o * 288 + k]);
        } else {                                     // W3B (2560)
            int jj = j - 82432;
            int kb = jj >> 9;
            int rest = jj & 511;
            int l = rest >> 3, j8 = rest & 7;
            int o = l & 15;
            int k = kb * 32 + ((l >> 4) << 3) + j8;
            W3B[jj] = __float2bfloat16((o == 0 && k < 144) ? W3[k] : 0.f);
        }
        return;
    }

    int w = blk & 7, bs = blk >> 3;
    int n0 = w * 512;
    const float* A = input + (size_t)bs * 36864;
    int base = n0 * 9;
    int cnt4 = min(4680, 36864 - base) >> 2;
    const float4* A4 = (const float4*)(A + base);
    float4* win4 = (float4*)win;
    for (int j = threadIdx.x; j < cnt4; j += 256) win4[j] = A4[j];
    if (threadIdx.x < 18) ((float4*)corner)[threadIdx.x] = ((const float4*)A)[threadIdx.x];
    __syncthreads();

    for (int i = threadIdx.x; i < 522; i += 256) {
        int j = i / 58, off = i - j * 58;
        int x = j * 4096 + n0;
        int pstart = (x + 8) / 9;
        int pend   = (x + 520) / 9;
        int p = pstart + off;
        if (p >= pend) continue;
        int nf = (p * 9) & 4095;
        float v[9];
        int wb = (nf - n0) * 9 + j;
        if (nf <= 4087) {
#pragma unroll
            for (int m = 0; m < 9; m++) v[m] = win[wb + 9 * m];
        } else {
            int nw = 4096 - nf;
#pragma unroll
            for (int m = 0; m < 9; m++)
                v[m] = (m < nw) ? win[wb + 9 * m]
                                : corner[(nf + m - 4096) * 9 + j + 1];
        }
        float acc[32];
#pragma unroll 4
        for (int c = 0; c < 32; c++) {
            float a = b1[c];
#pragma unroll
            for (int m = 0; m < 9; m++) a = fmaf(v[m], W1[c * 9 + m], a);
            acc[c] = fmaxf(a, 0.f);
        }
#pragma unroll
        for (int pl = 0; pl < 4; pl++) {
            uint4 d;
            d.x = (unsigned)bfbits(acc[pl * 8 + 0]) | ((unsigned)bfbits(acc[pl * 8 + 1]) << 16);
            d.y = (unsigned)bfbits(acc[pl * 8 + 2]) | ((unsigned)bfbits(acc[pl * 8 + 3]) << 16);
            d.z = (unsigned)bfbits(acc[pl * 8 + 4]) | ((unsigned)bfbits(acc[pl * 8 + 5]) << 16);
            d.w = (unsigned)bfbits(acc[pl * 8 + 6]) | ((unsigned)bfbits(acc[pl * 8 + 7]) << 16);
            hp[((size_t)pl * 192 + bs) * NN + p] = d;
        }
    }
}

// ---------------------------------------------------------------------------
// Kernel 2: layer 2 via MFMA, 512-thread WG per (bs, pl), R10-proven body +
// software pipelining: kb=0 idx/B-frag loads issued BEFORE the staging
// barrier (overlap global latency with LDS fill); in-loop rotation prefetches
// kb+1 while kb computes. Arithmetic identical to R10.
// ---------------------------------------------------------------------------
__global__ __launch_bounds__(512, 4) void k_layer2(const uint4* __restrict__ hp,
                                                   const int4* __restrict__ G2M4,
                                                   const int4* __restrict__ W2B4,
                                                   const float* __restrict__ b2,
                                                   __hip_bfloat16* __restrict__ y2p,
                                                   float* __restrict__ psum,
                                                   float* __restrict__ psq) {
    __shared__ __align__(16) uint4 hl[4096];       // 64 KB
    __shared__ float wred[2][8][16];
    int blk = blockIdx.x;                 // 768 = 192 bs * 4 pl
    int pl = blk & 3, bs = blk >> 2;

    int tid = threadIdx.x;
    int l = tid & 63, w = tid >> 6;       // w = r-tile 0..7
    int o = l & 15, q = l >> 4;

    // issue kb=0 index + B-frag loads BEFORE staging so their latency
    // overlaps the 64KB LDS fill
    const int4* gp = G2M4 + (size_t)(w * 9) * 128 + l * 2;
    int4 ia = gp[0];
    int4 ib = gp[1];
    U8 bf; bf.i = W2B4[l];

    const uint4* hb = hp + ((size_t)pl * 192 + bs) * NN;
    for (int j = tid; j < 4096; j += 512) hl[j] = hb[j];
    __syncthreads();

    float bb = b2[o];
    float s1 = 0.f, s2 = 0.f;
    __hip_bfloat16* ypl = y2p + (((size_t)(o >> 3) * 192 + bs) * NN) * 8 + (o & 7);

    f32x4 acc[8];
#pragma unroll
    for (int c = 0; c < 8; c++) acc[c] = (f32x4){0.f, 0.f, 0.f, 0.f};

#pragma unroll
    for (int kb = 0; kb < 9; kb++) {
        int4 na, nb; U8 nbf;
        if (kb < 8) {                     // prefetch kb+1 (folds at unroll)
            na = gp[(kb + 1) * 128];
            nb = gp[(kb + 1) * 128 + 1];
            nbf.i = W2B4[(kb + 1) * 64 + l];
        }
        Q d[8];
        d[0].v = hl[ia.x]; d[1].v = hl[ia.y]; d[2].v = hl[ia.z]; d[3].v = hl[ia.w];
        d[4].v = hl[ib.x]; d[5].v = hl[ib.y]; d[6].v = hl[ib.z]; d[7].v = hl[ib.w];
#pragma unroll
        for (int c = 0; c < 8; c++) {
            const int q2 = c >> 1;
            const unsigned sel = (c & 1) ? PERM_HI : PERM_LO;
            U8 Af;
            Af.i.x = __builtin_amdgcn_perm(d[1].u[q2], d[0].u[q2], sel);
            Af.i.y = __builtin_amdgcn_perm(d[3].u[q2], d[2].u[q2], sel);
            Af.i.z = __builtin_amdgcn_perm(d[5].u[q2], d[4].u[q2], sel);
            Af.i.w = __builtin_amdgcn_perm(d[7].u[q2], d[6].u[q2], sel);
            acc[c] = __builtin_amdgcn_mfma_f32_16x16x32_bf16(Af.b, bf.b, acc[c], 0, 0, 0);
        }
        if (kb < 8) { ia = na; ib = nb; bf = nbf; }
    }

    // proven epilogue: scattered bf16 stores into y2 octet planes
    int rbase = w * 16 + q * 4;
#pragma unroll
    for (int c = 0; c < 8; c++) {
        int C = pl * 8 + c;               // layer-2 input channel -> n-block
#pragma unroll
        for (int i = 0; i < 4; i++) {
            float v = acc[c][i] + bb;
            s1 += v; s2 += v * v;
            int n = C * 128 + rbase + i;
            ypl[(size_t)n * 8] = __float2bfloat16(v);
        }
    }

    s1 += __shfl_xor(s1, 16); s1 += __shfl_xor(s1, 32);
    s2 += __shfl_xor(s2, 16); s2 += __shfl_xor(s2, 32);
    if (l < 16) { wred[0][w][l] = s1; wred[1][w][l] = s2; }
    __syncthreads();
    if (tid < 16) {
        float a = 0.f, b = 0.f;
#pragma unroll
        for (int ww = 0; ww < 8; ww++) { a += wred[0][ww][tid]; b += wred[1][ww][tid]; }
        int srow = (bs % NS) * 16 + tid;
        int col  = (bs / NS) * 4 + pl;    // 32 cols
        psum[srow * 32 + col] = a;
        psq [srow * 32 + col] = b;
    }
}

// ---------------------------------------------------------------------------
// Kernel 3: fused BN-stat + BN + relu + layer 3 (MFMA) + relu, 512-thr WG
// per (bs, oct), R10-proven body + the same software pipelining.
// ---------------------------------------------------------------------------
__global__ __launch_bounds__(512, 4) void k_l3bn(const uint4* __restrict__ y2p,
                                                 const int4* __restrict__ G3M4,
                                                 const int4* __restrict__ W3B4,
                                                 const float* __restrict__ psum,
                                                 const float* __restrict__ psq,
                                                 const float* __restrict__ gamma,
                                                 const float* __restrict__ beta,
                                                 const float* __restrict__ b3,
                                                 float* __restrict__ out) {
    __shared__ __align__(16) uint4 zl[4096];       // 64 KB
    __shared__ float scl[8], shf[8];
    int blk = blockIdx.x;                 // 384 = 192 bs * 2 oct
    int oct = blk & 1, bs = blk >> 1;
    int s = bs % NS;
    int tid = threadIdx.x;

    if (tid < 256) {   // BN stat reduce: 8 rows x 32 cols, one value/thread
        int jj = tid >> 5, col = tid & 31;
        int row = s * 16 + oct * 8 + jj;
        float sv = psum[row * 32 + col];
        float qv = psq [row * 32 + col];
        for (int off = 16; off; off >>= 1) {
            sv += __shfl_down(sv, off, 32);
            qv += __shfl_down(qv, off, 32);
        }
        if (col == 0) {
            float mean = sv * (1.0f / BN_COUNT);
            float var  = qv * (1.0f / BN_COUNT) - mean * mean;
            float inv  = rsqrtf(var + 1e-5f);
            int o = oct * 8 + jj;
            float scv = gamma[o] * inv;
            scl[jj] = scv;
            shf[jj] = beta[o] - mean * scv;
        }
    }
    __syncthreads();

    float sc[8], sh[8];
#pragma unroll
    for (int jj = 0; jj < 8; jj++) { sc[jj] = scl[jj]; sh[jj] = shf[jj]; }

    int l = tid & 63, w = tid >> 6;       // w = 0..7
    int o = l & 15, q = l >> 4;

    // prefetch tt=0 / kb=0 idx + B-frag before staging
    const int4* gp0 = G3M4 + (size_t)(w * 5) * 128 + l * 2;       // t = w
    int4 ia = gp0[0];
    int4 ib = gp0[1];
    U8 bf; bf.i = W3B4[l];

    const uint4* yb = y2p + ((size_t)oct * 192 + bs) * NN;
    for (int j = tid; j < 4096; j += 512) {
        uint4 u = yb[j];
        unsigned r[4] = {u.x, u.y, u.z, u.w};
        uint4 pk;
        unsigned* pp = (unsigned*)&pk;
#pragma unroll
        for (int dd = 0; dd < 4; dd++) {
            float lo = fmaxf(fmaf(__uint_as_float(r[dd] << 16),         sc[dd*2],   sh[dd*2]),   0.f);
            float hi = fmaxf(fmaf(__uint_as_float(r[dd] & 0xffff0000u), sc[dd*2+1], sh[dd*2+1]), 0.f);
            unsigned ulo = __float_as_uint(lo) + 0x8000u;   // round to bf16
            unsigned uhi = __float_as_uint(hi) + 0x8000u;
            pp[dd] = __builtin_amdgcn_perm(uhi, ulo, PERM_HI);
        }
        zl[j] = pk;
    }
    __syncthreads();

    float b3v = b3[0];

#pragma unroll
    for (int tt = 0; tt < 2; tt++) {
        int t = tt * 8 + w;               // r-tile 0..15
        const int4* gp = G3M4 + (size_t)(t * 5) * 128 + l * 2;
        f32x4 acc[8];
#pragma unroll
        for (int c = 0; c < 8; c++) acc[c] = (f32x4){0.f, 0.f, 0.f, 0.f};
#pragma unroll
        for (int kb = 0; kb < 5; kb++) {
            int4 na, nb; U8 nbf;
            if (kb < 4) {                 // prefetch kb+1 within this tile
                na = gp[(kb + 1) * 128];
                nb = gp[(kb + 1) * 128 + 1];
                nbf.i = W3B4[(kb + 1) * 64 + l];
            } else if (tt == 0) {         // prefetch next tile's kb=0
                const int4* gpn = G3M4 + (size_t)((8 + w) * 5) * 128 + l * 2;
                na = gpn[0];
                nb = gpn[1];
                nbf.i = W3B4[l];
            }
            Q d[8];
            d[0].v = zl[ia.x]; d[1].v = zl[ia.y]; d[2].v = zl[ia.z]; d[3].v = zl[ia.w];
            d[4].v = zl[ib.x]; d[5].v = zl[ib.y]; d[6].v = zl[ib.z]; d[7].v = zl[ib.w];
#pragma unroll
            for (int c = 0; c < 8; c++) {
                const int q2 = c >> 1;
                const unsigned sel = (c & 1) ? PERM_HI : PERM_LO;
                U8 Af;
                Af.i.x = __builtin_amdgcn_perm(d[1].u[q2], d[0].u[q2], sel);
                Af.i.y = __builtin_amdgcn_perm(d[3].u[q2], d[2].u[q2], sel);
                Af.i.z = __builtin_amdgcn_perm(d[5].u[q2], d[4].u[q2], sel);
                Af.i.w = __builtin_amdgcn_perm(d[7].u[q2], d[6].u[q2], sel);
                acc[c] = __builtin_amdgcn_mfma_f32_16x16x32_bf16(Af.b, bf.b, acc[c], 0, 0, 0);
            }
            if (kb < 4 || tt == 0) { ia = na; ib = nb; bf = nbf; }
        }
        if (o == 0) {                     // C col 0 holds the result
            int rbase = t * 16 + q * 4;
            float* ob = out + (size_t)bs * NN + oct * 2048;
#pragma unroll
            for (int c = 0; c < 8; c++)
#pragma unroll
                for (int i = 0; i < 4; i++)
                    ob[c * 256 + rbase + i] = fmaxf(acc[c][i] + b3v, 0.f);
        }
    }
}

// ---------------------------------------------------------------------------
extern "C" void kernel_launch(void* const* d_in, const int* in_sizes, int n_in,
                              void* d_out, int out_size, void* d_ws, size_t ws_size,
                              hipStream_t stream) {
    const float* input = (const float*)d_in[0];
    const int*   neigh = (const int*)d_in[1];
    const float* W1    = (const float*)d_in[2];
    const float* b1    = (const float*)d_in[3];
    const float* W2    = (const float*)d_in[4];
    const float* b2    = (const float*)d_in[5];
    const float* gamma = (const float*)d_in[6];
    const float* beta  = (const float*)d_in[7];
    const float* W3    = (const float*)d_in[8];
    const float* b3    = (const float*)d_in[9];
    float* out = (float*)d_out;

    // Workspace layout (bytes), all 16B-aligned
    char* ws = (char*)d_ws;
    int*            G2M   = (int*)            (ws);             // 147456
    int*            G3M   = (int*)            (ws + 147456);    // 163840
    __hip_bfloat16* W2B   = (__hip_bfloat16*) (ws + 311296);    // 9216
    __hip_bfloat16* W3B   = (__hip_bfloat16*) (ws + 320512);    // 5120
    uint4*          h     = (uint4*)          (ws + 325632);    // 50331648
    __hip_bfloat16* y2    = (__hip_bfloat16*) (ws + 50657280);  // 25165824
    float*          psum  = (float*)          (ws + 75823104);  // 49152
    float*          psq   = (float*)          (ws + 75872256);  // 49152

    k_l1tab<<<1868, 256, 0, stream>>>(input, W1, b1, h,
                                      neigh, G2M, G3M, W2, W3, W2B, W3B);
    k_layer2<<<768, 512, 0, stream>>>(h, (const int4*)G2M, (const int4*)W2B,
                                      b2, y2, psum, psq);
    k_l3bn<<<384, 512, 0, stream>>>((const uint4*)y2, (const int4*)G3M,
                                    (const int4*)W3B, psum, psq,
                                    gamma, beta, b3, out);
}